// Round 20
// baseline (367.530 us; speedup 1.0000x reference)
//
#include <hip/hip_runtime.h>
#include <stdint.h>

// ---------------------------------------------------------------------------
// TransformerEncoderLayer: b=4 s=2048 d=128 h=8 (head_dim=128) dff=2048
// Round-20 (r19 post-mortem: ffn 8-wave split regressed; qkv B-staging won):
//  - k_ffn: REVERT to r16 proven 63us version (4-wave, LDS dump reduce).
//  - k_attn: kv-split x4 -> grid (16,8,4)=512 blocks = 2 blocks/CU
//    (LDS 80KB allows 2; grid was the occupancy cap). O quarters.
//  - k_oproj: inline 4-way combine.
//  - qkv: A-loads back to f32 x (xb dropped to keep ws at 30.6 MiB).
// ---------------------------------------------------------------------------

using f32x4 = __attribute__((ext_vector_type(4))) float;
using s16x8 = __attribute__((ext_vector_type(8))) short;
using s16x4 = __attribute__((ext_vector_type(4))) short;
typedef __bf16 bf16x8 __attribute__((ext_vector_type(8)));

__device__ inline void mfma_bf16(f32x4* acc, s16x8 a, s16x8 b) {
    *acc = __builtin_amdgcn_mfma_f32_16x16x32_bf16(
        __builtin_bit_cast(bf16x8, a), __builtin_bit_cast(bf16x8, b), *acc, 0, 0, 0);
}

__device__ inline short f2bf(float f) {   // RNE f32 -> bf16 bits
    uint32_t u = __builtin_bit_cast(uint32_t, f);
    u += 0x7fffu + ((u >> 16) & 1u);
    return (short)(u >> 16);
}

__device__ inline float bf2f(short s) {
    return __builtin_bit_cast(float, (uint32_t)((uint16_t)s) << 16);
}

// async global->LDS, 16B per lane; LDS dest = wave-uniform base + lane*16
__device__ inline void gload16(const short* g, short* l) {
    __builtin_amdgcn_global_load_lds(
        (const __attribute__((address_space(1))) void*)g,
        (__attribute__((address_space(3))) void*)l, 16, 0, 0);
}

// ---------------- ALL weight transposes, one launch ------------------------
__global__ __launch_bounds__(256) void k_transpose_all(
    const float* __restrict__ Wq, const float* __restrict__ Wk,
    const float* __restrict__ Wv, const float* __restrict__ Wo,
    const float* __restrict__ W1, const float* __restrict__ W2,
    short* __restrict__ WqT, short* __restrict__ WkT, short* __restrict__ WvT,
    short* __restrict__ WoT, short* __restrict__ W1T, short* __restrict__ W2T)
{
    int b = blockIdx.x;
    const float* w; short* wt; int R, lc, lb;
    if (b < 512)       { w = Wq; wt = WqT; R = 128;  lc = 10; lb = 0;    }
    else if (b < 1024) { w = Wk; wt = WkT; R = 128;  lc = 10; lb = 512;  }
    else if (b < 1536) { w = Wv; wt = WvT; R = 128;  lc = 10; lb = 1024; }
    else if (b < 2048) { w = Wo; wt = WoT; R = 1024; lc = 7;  lb = 1536; }
    else if (b < 3072) { w = W1; wt = W1T; R = 128;  lc = 11; lb = 2048; }
    else               { w = W2; wt = W2T; R = 2048; lc = 7;  lb = 3072; }
    int i = (b - lb) * 256 + threadIdx.x;
    int r = i >> lc, c = i & ((1 << lc) - 1);
    wt[c * R + r] = f2bf(w[i]);
}

// ---------------- QKV projection (one batch, ALL 8 heads) ------------------
// B-tile staged via global_load_lds (source-folded swizzle). A from f32 x.
__global__ __launch_bounds__(256) void k_qkv(
    const float* __restrict__ xB, const short* __restrict__ WqT,
    const short* __restrict__ WkT, const short* __restrict__ WvT,
    short* __restrict__ Qh, short* __restrict__ Kh, short* __restrict__ Vt)
{
    __shared__ __align__(16) short Bls[64 * 128];   // swizzled [col][k]
    const int z = blockIdx.z;
    const short* __restrict__ WT = (z == 0) ? WqT : (z == 1) ? WkT : WvT; // [1024][128]
    const int w = threadIdx.x >> 6, lane = threadIdx.x & 63;
    const int g = lane >> 4, li = lane & 15;
    const int m0 = blockIdx.x * 64 + w * 16;
    const int n0 = blockIdx.y * 64;               // 0..960

    #pragma unroll
    for (int c2 = 0; c2 < 4; ++c2) {
        int ci = c2 * 256 + (int)threadIdx.x;
        int row = ci >> 4, cc = ci & 15;
        gload16(WT + (size_t)(n0 + row) * 128 + ((cc ^ (row & 7)) * 8),
                &Bls[(c2 * 256 + w * 64) * 8]);
    }
    __syncthreads();

    f32x4 acc[4] = {};
    #pragma unroll
    for (int ks = 0; ks < 4; ++ks) {
        const float* xr = xB + (size_t)(m0 + li) * 128 + ks * 32 + g * 8;
        float4 v0 = *(const float4*)xr, v1 = *(const float4*)(xr + 4);
        s16x8 a = { f2bf(v0.x), f2bf(v0.y), f2bf(v0.z), f2bf(v0.w),
                    f2bf(v1.x), f2bf(v1.y), f2bf(v1.z), f2bf(v1.w) };
        #pragma unroll
        for (int nt = 0; nt < 4; ++nt) {
            s16x8 bfr = *(const s16x8*)&Bls[(nt * 16 + li) * 128
                                            + (((ks * 4 + g) ^ (li & 7)) * 8)];
            mfma_bf16(&acc[nt], a, bfr);
        }
    }
    const float sc = (z == 0) ? 0.088388347648318447f : 1.0f; // 1/sqrt(128) into Q
    #pragma unroll
    for (int nt = 0; nt < 4; ++nt) {
        int col = n0 + nt * 16 + li;              // 0..1023
        int hh = col >> 7, dd = col & 127;        // head, dim
        if (z == 2) {
            int row0 = m0 + g * 4;                // s, multiple of 4
            int kt = row0 >> 6, so = row0 & 63;
            s16x4 o = { f2bf(acc[nt][0]), f2bf(acc[nt][1]),
                        f2bf(acc[nt][2]), f2bf(acc[nt][3]) };
            *(s16x4*)(Vt + (((size_t)hh * 32 + kt) * 128 + dd) * 64 + so) = o;
        } else {
            short* __restrict__ dst = (z == 0) ? Qh : Kh;
            #pragma unroll
            for (int r = 0; r < 4; ++r)
                dst[((size_t)hh * 2048 + m0 + g * 4 + r) * 128 + dd] =
                    f2bf(acc[nt][r] * sc);
        }
    }
}

// ---------------- flash attention, 8 waves/block, kv-split x4 --------------
// grid (16 qblocks of 128 rows, 8 heads, 4 kv-quarters) = 512 blocks x 512 thr
// = 2 blocks/CU (LDS 80KB). Each quarter: 8 kv tiles; O quarter + (m,l)/row.
__global__ __launch_bounds__(512) void k_attn(
    const short* __restrict__ Qh, const short* __restrict__ Kh,
    const short* __restrict__ Vt, short* __restrict__ O,
    float2* __restrict__ ml)
{
    __shared__ __align__(16) short Kls[2][64 * 128];   // swizzled [k][d], dbuf
    __shared__ __align__(16) short Vls[2][128 * 64];   // swizzled [d][k], dbuf
    __shared__ __align__(16) short Pls[8][16 * 64];    // per-wave swizzled [q][k]
    const int hh = blockIdx.y;
    const int qr = blockIdx.z;                         // kv quarter
    const size_t base  = (size_t)hh * 2048 * 128;
    const size_t vbase = (size_t)hh * 32 * 8192;       // tile-blocked V^T
    const int w = threadIdx.x >> 6, lane = threadIdx.x & 63;
    const int g = lane >> 4, li = lane & 15;
    const int q0 = blockIdx.x * 128;
    const int qw = q0 + w * 16;
    const int kt0 = qr * 8;

    #define STAGE(BUF, KT)                                                      \
        { _Pragma("unroll")                                                     \
          for (int c2 = 0; c2 < 2; ++c2) {                                      \
              int ci = c2 * 512 + (int)threadIdx.x;                             \
              int row = ci >> 4, cc = ci & 15;                                  \
              gload16(Kh + base + (size_t)((KT) * 64 + row) * 128               \
                         + ((cc ^ (row & 7)) * 8),                              \
                      &Kls[BUF][(c2 * 512 + w * 64) * 8]);                      \
              int d = ci >> 3, jc = ci & 7;                                     \
              gload16(Vt + vbase + (size_t)(KT) * 8192 + d * 64                 \
                         + ((jc ^ (d & 7)) * 8),                                \
                      &Vls[BUF][(c2 * 512 + w * 64) * 8]);                      \
          } }

    s16x8 qf[4];
    #pragma unroll
    for (int ks = 0; ks < 4; ++ks)
        qf[ks] = *(const s16x8*)(Qh + base + (size_t)(qw + li) * 128 + ks * 32 + g * 8);

    f32x4 acc[8] = {};
    float mrow[4] = { -1e30f, -1e30f, -1e30f, -1e30f };
    float lpart[4] = { 0.f, 0.f, 0.f, 0.f };    // PER-LANE partial of l

    STAGE(0, kt0);
    for (int t = 0; t < 8; ++t) {
        const int cur = t & 1;
        __syncthreads();                  // drains vmcnt: buf[cur] ready
        if (t + 1 < 8) STAGE(cur ^ 1, kt0 + t + 1);   // in flight during compute

        f32x4 st[4];
        __builtin_amdgcn_s_setprio(1);
        #pragma unroll
        for (int nt = 0; nt < 4; ++nt) {
            st[nt] = (f32x4){0.f, 0.f, 0.f, 0.f};
            #pragma unroll
            for (int ks = 0; ks < 4; ++ks) {
                s16x8 bfr = *(const s16x8*)&Kls[cur][(nt * 16 + li) * 128
                                                + (((ks * 4 + g) ^ (li & 7)) * 8)];
                mfma_bf16(&st[nt], qf[ks], bfr);
            }
        }
        __builtin_amdgcn_s_setprio(0);

        float mxl[4];
        bool cond = true;
        #pragma unroll
        for (int r = 0; r < 4; ++r) {
            mxl[r] = fmaxf(fmaxf(st[0][r], st[1][r]), fmaxf(st[2][r], st[3][r]));
            cond = cond && (mxl[r] <= mrow[r] + 8.f);
        }
        if (__all(cond)) {
            #pragma unroll
            for (int r = 0; r < 4; ++r) {
                float rs = 0.f;
                #pragma unroll
                for (int nt = 0; nt < 4; ++nt) {
                    float p = __expf(st[nt][r] - mrow[r]);
                    st[nt][r] = p;
                    rs += p;
                }
                lpart[r] += rs;
            }
        } else {
            #pragma unroll
            for (int r = 0; r < 4; ++r) {
                float mx = mxl[r];
                mx = fmaxf(mx, __shfl_xor(mx, 1));
                mx = fmaxf(mx, __shfl_xor(mx, 2));
                mx = fmaxf(mx, __shfl_xor(mx, 4));
                mx = fmaxf(mx, __shfl_xor(mx, 8));
                float mnew = fmaxf(mrow[r], mx);
                float alpha = __expf(mrow[r] - mnew);
                float rs = 0.f;
                #pragma unroll
                for (int nt = 0; nt < 4; ++nt) {
                    float p = __expf(st[nt][r] - mnew);
                    st[nt][r] = p;
                    rs += p;
                }
                lpart[r] = lpart[r] * alpha + rs;   // alpha row-uniform
                mrow[r] = mnew;
                #pragma unroll
                for (int dt = 0; dt < 8; ++dt) acc[dt][r] *= alpha;
            }
        }

        short* pw = Pls[w];
        #pragma unroll
        for (int nt = 0; nt < 4; ++nt)
            #pragma unroll
            for (int r = 0; r < 4; ++r) {
                int row = g * 4 + r;
                pw[row * 64 + (((nt * 2 + (li >> 3)) ^ (row & 7)) * 8) + (li & 7)]
                    = f2bf(st[nt][r]);
            }
        __builtin_amdgcn_s_setprio(1);
        #pragma unroll
        for (int kk = 0; kk < 2; ++kk) {
            s16x8 af = *(const s16x8*)&pw[li * 64 + (((kk * 4 + g) ^ (li & 7)) * 8)];
            #pragma unroll
            for (int dt = 0; dt < 8; ++dt) {
                s16x8 bfr = *(const s16x8*)&Vls[cur][(dt * 16 + li) * 64
                                                + (((kk * 4 + g) ^ (li & 7)) * 8)];
                mfma_bf16(&acc[dt], af, bfr);
            }
        }
        __builtin_amdgcn_s_setprio(0);
    }
    #undef STAGE

    float lrow[4];
    #pragma unroll
    for (int r = 0; r < 4; ++r) {
        float rs = lpart[r];
        rs += __shfl_xor(rs, 1);
        rs += __shfl_xor(rs, 2);
        rs += __shfl_xor(rs, 4);
        rs += __shfl_xor(rs, 8);
        lrow[r] = rs;
    }
    short* __restrict__ Op = O + (size_t)qr * 2048 * 1024;
    float2* __restrict__ mlp = ml + (size_t)qr * 8 * 2048;
    #pragma unroll
    for (int r = 0; r < 4; ++r) {
        int row = q0 + w * 16 + g * 4 + r;
        if (li == 0) mlp[hh * 2048 + row] = make_float2(mrow[r], lrow[r]);
        #pragma unroll
        for (int dt = 0; dt < 8; ++dt)
            Op[(size_t)row * 1024 + hh * 128 + dt * 16 + li] = f2bf(acc[dt][r]);
    }
}

// ---------------- fused 4-way combine + out-proj + residual + LN1 ----------
// per batch: grid 128 blocks x 256 thr; block owns 16 rows; 4-wave K-split.
__global__ __launch_bounds__(256) void k_oproj(
    const short* __restrict__ O, const float2* __restrict__ ml,
    const short* __restrict__ WoT, const float* __restrict__ resid,
    const float* __restrict__ gain, float* __restrict__ outp)
{
    __shared__ float red[3][16 * 128];            // 24 KB partial-acc dump
    const int w = threadIdx.x >> 6, lane = threadIdx.x & 63;
    const int g = lane >> 4, li = lane & 15;
    const int m0 = blockIdx.x * 16;
    const int row = m0 + li;
    float e[2][4], il[2];                         // this wave's 2 heads
    #pragma unroll
    for (int hi = 0; hi < 2; ++hi) {
        int h = w * 2 + hi;
        float2 a0 = ml[0 * 16384 + h * 2048 + row];
        float2 a1 = ml[1 * 16384 + h * 2048 + row];
        float2 a2 = ml[2 * 16384 + h * 2048 + row];
        float2 a3 = ml[3 * 16384 + h * 2048 + row];
        float M = fmaxf(fmaxf(a0.x, a1.x), fmaxf(a2.x, a3.x));
        e[hi][0] = __expf(a0.x - M); e[hi][1] = __expf(a1.x - M);
        e[hi][2] = __expf(a2.x - M); e[hi][3] = __expf(a3.x - M);
        il[hi] = 1.f / (a0.y * e[hi][0] + a1.y * e[hi][1]
                      + a2.y * e[hi][2] + a3.y * e[hi][3]);
    }
    f32x4 acc[8] = {};
    #pragma unroll
    for (int kq = 0; kq < 8; ++kq) {              // ks = w*8 + kq
        int ks = w * 8 + kq;
        int hi = kq >> 2;
        size_t aoff = (size_t)row * 1024 + ks * 32 + g * 8;
        s16x8 a0 = *(const s16x8*)(O + 0ull * 2097152 + aoff);
        s16x8 a1 = *(const s16x8*)(O + 1ull * 2097152 + aoff);
        s16x8 a2 = *(const s16x8*)(O + 2ull * 2097152 + aoff);
        s16x8 a3 = *(const s16x8*)(O + 3ull * 2097152 + aoff);
        s16x8 a;
        #pragma unroll
        for (int ee = 0; ee < 8; ++ee)
            a[ee] = f2bf((bf2f(a0[ee]) * e[hi][0] + bf2f(a1[ee]) * e[hi][1]
                        + bf2f(a2[ee]) * e[hi][2] + bf2f(a3[ee]) * e[hi][3])
                         * il[hi]);
        #pragma unroll
        for (int nt = 0; nt < 8; ++nt) {
            s16x8 bfr = *(const s16x8*)(WoT + (size_t)(nt * 16 + li) * 1024
                                           + ks * 32 + g * 8);
            mfma_bf16(&acc[nt], a, bfr);
        }
    }
    if (w > 0) {
        #pragma unroll
        for (int nt = 0; nt < 8; ++nt)
            #pragma unroll
            for (int r = 0; r < 4; ++r)
                red[w - 1][(g * 4 + r) * 128 + nt * 16 + li] = acc[nt][r];
    }
    __syncthreads();
    if (w == 0) {
        float gv[8];
        #pragma unroll
        for (int nt = 0; nt < 8; ++nt) gv[nt] = gain[nt * 16 + li];
        #pragma unroll
        for (int r = 0; r < 4; ++r) {
            int orow = m0 + g * 4 + r;
            float s = 0.f, s2 = 0.f;
            #pragma unroll
            for (int nt = 0; nt < 8; ++nt) {
                float v = acc[nt][r]
                        + red[0][(g * 4 + r) * 128 + nt * 16 + li]
                        + red[1][(g * 4 + r) * 128 + nt * 16 + li]
                        + red[2][(g * 4 + r) * 128 + nt * 16 + li]
                        + resid[(size_t)orow * 128 + nt * 16 + li];
                acc[nt][r] = v;
                s += v; s2 += v * v;
            }
            s  += __shfl_xor(s, 1);  s  += __shfl_xor(s, 2);
            s  += __shfl_xor(s, 4);  s  += __shfl_xor(s, 8);
            s2 += __shfl_xor(s2, 1); s2 += __shfl_xor(s2, 2);
            s2 += __shfl_xor(s2, 4); s2 += __shfl_xor(s2, 8);
            float mean = s * (1.f / 128.f);
            float var  = s2 * (1.f / 128.f) - mean * mean;
            float rstd = rsqrtf(var + 1e-5f);
            #pragma unroll
            for (int nt = 0; nt < 8; ++nt)
                outp[(size_t)orow * 128 + nt * 16 + li] =
                    (acc[nt][r] - mean) * rstd * gv[nt];
        }
    }
}

// ---------------- fused FFN (r16 proven 63us version) ----------------------
// ALL batches: grid (64, 4) x 256 thr; block owns 32 rows; 4-wave dff-split.
__global__ __launch_bounds__(256) void k_ffn(
    const float* __restrict__ x1, const short* __restrict__ W1T,
    const short* __restrict__ W2T, const float* __restrict__ gain,
    float* __restrict__ outp)
{
    __shared__ __align__(16) short hls[4][2][16 * 64]; // [wave][mt], swizzled
    __shared__ float red[3][2][16 * 128];              // 48 KB partial-acc dump
    const int w = threadIdx.x >> 6, lane = threadIdx.x & 63;
    const int g = lane >> 4, li = lane & 15;
    const size_t m0 = (size_t)blockIdx.y * 2048 + blockIdx.x * 32;
    s16x8 xf[2][4];
    #pragma unroll
    for (int mt = 0; mt < 2; ++mt)
        #pragma unroll
        for (int ks = 0; ks < 4; ++ks) {
            const float* xr = x1 + (m0 + mt * 16 + li) * 128 + ks * 32 + g * 8;
            float4 v0 = *(const float4*)xr, v1 = *(const float4*)(xr + 4);
            xf[mt][ks] = (s16x8){ f2bf(v0.x), f2bf(v0.y), f2bf(v0.z), f2bf(v0.w),
                                  f2bf(v1.x), f2bf(v1.y), f2bf(v1.z), f2bf(v1.w) };
        }
    f32x4 acc[2][8] = {};
    #pragma unroll 2
    for (int cq = 0; cq < 8; ++cq) {              // ch = w*8 + cq
        int ch = w * 8 + cq;
        f32x4 st[2][4] = {};
        #pragma unroll
        for (int nt = 0; nt < 4; ++nt)
            #pragma unroll
            for (int ks = 0; ks < 4; ++ks) {
                s16x8 bfr = *(const s16x8*)(W1T + (size_t)(ch * 64 + nt * 16 + li) * 128
                                               + ks * 32 + g * 8);
                mfma_bf16(&st[0][nt], xf[0][ks], bfr);
                mfma_bf16(&st[1][nt], xf[1][ks], bfr);
            }
        #pragma unroll
        for (int mt = 0; mt < 2; ++mt) {
            short* hw = hls[w][mt];
            #pragma unroll
            for (int nt = 0; nt < 4; ++nt)
                #pragma unroll
                for (int r = 0; r < 4; ++r) {
                    int rw = g * 4 + r;
                    hw[rw * 64 + (((nt * 2 + (li >> 3)) ^ (rw & 7)) * 8) + (li & 7)]
                        = f2bf(fmaxf(st[mt][nt][r], 0.f));
                }
        }
        #pragma unroll
        for (int kk = 0; kk < 2; ++kk) {
            s16x8 af0 = *(const s16x8*)&hls[w][0][li * 64
                                                  + (((kk * 4 + g) ^ (li & 7)) * 8)];
            s16x8 af1 = *(const s16x8*)&hls[w][1][li * 64
                                                  + (((kk * 4 + g) ^ (li & 7)) * 8)];
            #pragma unroll
            for (int nt = 0; nt < 8; ++nt) {
                s16x8 bfr = *(const s16x8*)(W2T + (size_t)(nt * 16 + li) * 2048
                                               + ch * 64 + kk * 32 + g * 8);
                mfma_bf16(&acc[0][nt], af0, bfr);
                mfma_bf16(&acc[1][nt], af1, bfr);
            }
        }
    }
    if (w > 0) {
        #pragma unroll
        for (int mt = 0; mt < 2; ++mt)
            #pragma unroll
            for (int nt = 0; nt < 8; ++nt)
                #pragma unroll
                for (int r = 0; r < 4; ++r)
                    red[w - 1][mt][(g * 4 + r) * 128 + nt * 16 + li] = acc[mt][nt][r];
    }
    __syncthreads();
    if (w == 0) {
        float gv[8];
        #pragma unroll
        for (int nt = 0; nt < 8; ++nt) gv[nt] = gain[nt * 16 + li];
        #pragma unroll
        for (int mt = 0; mt < 2; ++mt)
            #pragma unroll
            for (int r = 0; r < 4; ++r) {
                size_t orow = m0 + mt * 16 + g * 4 + r;
                float s = 0.f, s2 = 0.f;
                #pragma unroll
                for (int nt = 0; nt < 8; ++nt) {
                    float v = acc[mt][nt][r]
                            + red[0][mt][(g * 4 + r) * 128 + nt * 16 + li]
                            + red[1][mt][(g * 4 + r) * 128 + nt * 16 + li]
                            + red[2][mt][(g * 4 + r) * 128 + nt * 16 + li]
                            + x1[orow * 128 + nt * 16 + li];
                    acc[mt][nt][r] = v;
                    s += v; s2 += v * v;
                }
                s  += __shfl_xor(s, 1);  s  += __shfl_xor(s, 2);
                s  += __shfl_xor(s, 4);  s  += __shfl_xor(s, 8);
                s2 += __shfl_xor(s2, 1); s2 += __shfl_xor(s2, 2);
                s2 += __shfl_xor(s2, 4); s2 += __shfl_xor(s2, 8);
                float mean = s * (1.f / 128.f);
                float var  = s2 * (1.f / 128.f) - mean * mean;
                float rstd = rsqrtf(var + 1e-5f);
                #pragma unroll
                for (int nt = 0; nt < 8; ++nt)
                    outp[orow * 128 + nt * 16 + li] =
                        (acc[mt][nt][r] - mean) * rstd * gv[nt];
            }
    }
}

// ---------------------------------------------------------------------------
extern "C" void kernel_launch(void* const* d_in, const int* in_sizes, int n_in,
                              void* d_out, int out_size, void* d_ws, size_t ws_size,
                              hipStream_t stream)
{
    const float* x  = (const float*)d_in[0];
    const float* Wq = (const float*)d_in[1];
    const float* Wk = (const float*)d_in[2];
    const float* Wv = (const float*)d_in[3];
    const float* Wo = (const float*)d_in[4];
    const float* W1 = (const float*)d_in[5];
    const float* W2 = (const float*)d_in[6];
    const float* g1 = (const float*)d_in[7];
    const float* g2 = (const float*)d_in[8];
    float* out = (float*)d_out;
    (void)in_sizes; (void)n_in; (void)out_size; (void)ws_size;

    char* basep = (char*)d_ws;
    size_t off = 0;
    auto carve = [&](size_t bytes) {
        void* q = basep + off;
        off += (bytes + 255) & ~(size_t)255;
        return q;
    };
    // total ~30.6 MiB (green proven 26.3; fail located <45.2)
    short*  WqT = (short*)carve(1024ull * 128 * 2);
    short*  WkT = (short*)carve(1024ull * 128 * 2);
    short*  WvT = (short*)carve(1024ull * 128 * 2);
    short*  WoT = (short*)carve(128ull * 1024 * 2);
    short*  W1T = (short*)carve(2048ull * 128 * 2);
    short*  W2T = (short*)carve(128ull * 2048 * 2);
    short*  Qh  = (short*)carve(8ull * 2048 * 128 * 2);   // 4 MiB
    short*  Kh  = (short*)carve(8ull * 2048 * 128 * 2);   // 4 MiB
    short*  Vt  = (short*)carve(8ull * 32 * 128 * 64 * 2);// 4 MiB
    short*  O   = (short*)carve(4ull * 2048 * 1024 * 2);  // 16 MiB (4 quarters)
    float2* ml  = (float2*)carve(4ull * 8 * 2048 * 8);    // 512 KiB

    k_transpose_all<<<4096, 256, 0, stream>>>(Wq, Wk, Wv, Wo, W1, W2,
                                              WqT, WkT, WvT, WoT, W1T, W2T);

    for (int b = 0; b < 4; ++b) {
        const float* xf32 = x + (size_t)b * 2048 * 128;
        float* x1b = out + (size_t)b * 2048 * 128;
        k_qkv<<<dim3(32, 16, 3), 256, 0, stream>>>(xf32, WqT, WkT, WvT,
                                                   Qh, Kh, Vt);
        k_attn<<<dim3(16, 8, 4), 512, 0, stream>>>(Qh, Kh, Vt, O, ml);
        k_oproj<<<128, 256, 0, stream>>>(O, ml, WoT, xf32, g1, x1b);
    }

    k_ffn<<<dim3(64, 4), 256, 0, stream>>>(out, W1T, W2T, g2, out);
}

// Round 21
// 357.169 us; speedup vs baseline: 1.0290x; 1.0290x over previous
//
#include <hip/hip_runtime.h>
#include <stdint.h>

// ---------------------------------------------------------------------------
// TransformerEncoderLayer: b=4 s=2048 d=128 h=8 (head_dim=128) dff=2048
// Round-21 (r20 post-mortem: kv4+4-way-combine regressed stage A):
//  - REVERT to best-known hybrid: r19 stage A (qkv: bf16 xb A + LDS B-staging;
//    attn: kv-split x2, QBLK=128; oproj: 2-way combine) + r16 ffn (63us).
//  - exp2-domain softmax: log2e folded into Q scale; exp->exp2 everywhere
//    (saves the v_mul inside every __expf; combine uses exp2f consistently).
// ---------------------------------------------------------------------------

using f32x4 = __attribute__((ext_vector_type(4))) float;
using s16x8 = __attribute__((ext_vector_type(8))) short;
using s16x4 = __attribute__((ext_vector_type(4))) short;
typedef __bf16 bf16x8 __attribute__((ext_vector_type(8)));

__device__ inline void mfma_bf16(f32x4* acc, s16x8 a, s16x8 b) {
    *acc = __builtin_amdgcn_mfma_f32_16x16x32_bf16(
        __builtin_bit_cast(bf16x8, a), __builtin_bit_cast(bf16x8, b), *acc, 0, 0, 0);
}

__device__ inline short f2bf(float f) {   // RNE f32 -> bf16 bits
    uint32_t u = __builtin_bit_cast(uint32_t, f);
    u += 0x7fffu + ((u >> 16) & 1u);
    return (short)(u >> 16);
}

__device__ inline float bf2f(short s) {
    return __builtin_bit_cast(float, (uint32_t)((uint16_t)s) << 16);
}

// async global->LDS, 16B per lane; LDS dest = wave-uniform base + lane*16
__device__ inline void gload16(const short* g, short* l) {
    __builtin_amdgcn_global_load_lds(
        (const __attribute__((address_space(1))) void*)g,
        (__attribute__((address_space(3))) void*)l, 16, 0, 0);
}

// ---------------- x f32 -> bf16 (all batches, one launch) ------------------
__global__ __launch_bounds__(256) void k_cvt(const float* __restrict__ x,
                                             short* __restrict__ xb) {
    int i = (blockIdx.x * 256 + threadIdx.x) * 4;
    float4 v = *(const float4*)(x + i);
    s16x4 o = { f2bf(v.x), f2bf(v.y), f2bf(v.z), f2bf(v.w) };
    *(s16x4*)(xb + i) = o;
}

// ---------------- ALL weight transposes, one launch ------------------------
__global__ __launch_bounds__(256) void k_transpose_all(
    const float* __restrict__ Wq, const float* __restrict__ Wk,
    const float* __restrict__ Wv, const float* __restrict__ Wo,
    const float* __restrict__ W1, const float* __restrict__ W2,
    short* __restrict__ WqT, short* __restrict__ WkT, short* __restrict__ WvT,
    short* __restrict__ WoT, short* __restrict__ W1T, short* __restrict__ W2T)
{
    int b = blockIdx.x;
    const float* w; short* wt; int R, lc, lb;
    if (b < 512)       { w = Wq; wt = WqT; R = 128;  lc = 10; lb = 0;    }
    else if (b < 1024) { w = Wk; wt = WkT; R = 128;  lc = 10; lb = 512;  }
    else if (b < 1536) { w = Wv; wt = WvT; R = 128;  lc = 10; lb = 1024; }
    else if (b < 2048) { w = Wo; wt = WoT; R = 1024; lc = 7;  lb = 1536; }
    else if (b < 3072) { w = W1; wt = W1T; R = 128;  lc = 11; lb = 2048; }
    else               { w = W2; wt = W2T; R = 2048; lc = 7;  lb = 3072; }
    int i = (b - lb) * 256 + threadIdx.x;
    int r = i >> lc, c = i & ((1 << lc) - 1);
    wt[c * R + r] = f2bf(w[i]);
}

// ---------------- QKV projection (one batch, ALL 8 heads) ------------------
// A from bf16 xb; B-tile staged via global_load_lds (source-folded swizzle).
// Q pre-scaled by log2(e)/sqrt(d) (exp2-domain softmax downstream).
__global__ __launch_bounds__(256) void k_qkv(
    const short* __restrict__ xbB, const short* __restrict__ WqT,
    const short* __restrict__ WkT, const short* __restrict__ WvT,
    short* __restrict__ Qh, short* __restrict__ Kh, short* __restrict__ Vt)
{
    __shared__ __align__(16) short Bls[64 * 128];   // swizzled [col][k]
    const int z = blockIdx.z;
    const short* __restrict__ WT = (z == 0) ? WqT : (z == 1) ? WkT : WvT; // [1024][128]
    const int w = threadIdx.x >> 6, lane = threadIdx.x & 63;
    const int g = lane >> 4, li = lane & 15;
    const int m0 = blockIdx.x * 64 + w * 16;
    const int n0 = blockIdx.y * 64;               // 0..960

    #pragma unroll
    for (int c2 = 0; c2 < 4; ++c2) {
        int ci = c2 * 256 + (int)threadIdx.x;
        int row = ci >> 4, cc = ci & 15;
        gload16(WT + (size_t)(n0 + row) * 128 + ((cc ^ (row & 7)) * 8),
                &Bls[(c2 * 256 + w * 64) * 8]);
    }
    __syncthreads();

    f32x4 acc[4] = {};
    #pragma unroll
    for (int ks = 0; ks < 4; ++ks) {
        s16x8 a = *(const s16x8*)(xbB + (size_t)(m0 + li) * 128 + ks * 32 + g * 8);
        #pragma unroll
        for (int nt = 0; nt < 4; ++nt) {
            s16x8 bfr = *(const s16x8*)&Bls[(nt * 16 + li) * 128
                                            + (((ks * 4 + g) ^ (li & 7)) * 8)];
            mfma_bf16(&acc[nt], a, bfr);
        }
    }
    // 1/sqrt(128) * log2(e) folded into Q (scores land in log2 domain)
    const float sc = (z == 0) ? 0.12751879524622257f : 1.0f;
    #pragma unroll
    for (int nt = 0; nt < 4; ++nt) {
        int col = n0 + nt * 16 + li;              // 0..1023
        int hh = col >> 7, dd = col & 127;        // head, dim
        if (z == 2) {
            int row0 = m0 + g * 4;                // s, multiple of 4
            int kt = row0 >> 6, so = row0 & 63;
            s16x4 o = { f2bf(acc[nt][0]), f2bf(acc[nt][1]),
                        f2bf(acc[nt][2]), f2bf(acc[nt][3]) };
            *(s16x4*)(Vt + (((size_t)hh * 32 + kt) * 128 + dd) * 64 + so) = o;
        } else {
            short* __restrict__ dst = (z == 0) ? Qh : Kh;
            #pragma unroll
            for (int r = 0; r < 4; ++r)
                dst[((size_t)hh * 2048 + m0 + g * 4 + r) * 128 + dd] =
                    f2bf(acc[nt][r] * sc);
        }
    }
}

// ---------------- flash attention, 8 waves/block (QBLK=128), kv-split x2 ---
// grid (16 qblocks of 128 rows, 8 heads, 2 kv-halves) = 256 blocks x 512 thr.
// Softmax fully in exp2 domain (Q carries log2e).
__global__ __launch_bounds__(512) void k_attn(
    const short* __restrict__ Qh, const short* __restrict__ Kh,
    const short* __restrict__ Vt, short* __restrict__ O0,
    short* __restrict__ O1, float2* __restrict__ ml0, float2* __restrict__ ml1)
{
    __shared__ __align__(16) short Kls[2][64 * 128];   // swizzled [k][d], dbuf
    __shared__ __align__(16) short Vls[2][128 * 64];   // swizzled [d][k], dbuf
    __shared__ __align__(16) short Pls[8][16 * 64];    // per-wave swizzled [q][k]
    const int hh = blockIdx.y;
    const int half = blockIdx.z;
    const size_t base  = (size_t)hh * 2048 * 128;
    const size_t vbase = (size_t)hh * 32 * 8192;       // tile-blocked V^T
    const int w = threadIdx.x >> 6, lane = threadIdx.x & 63;
    const int g = lane >> 4, li = lane & 15;
    const int q0 = blockIdx.x * 128;
    const int qw = q0 + w * 16;
    const int kt0 = half * 16;

    #define STAGE(BUF, KT)                                                      \
        { _Pragma("unroll")                                                     \
          for (int c2 = 0; c2 < 2; ++c2) {                                      \
              int ci = c2 * 512 + (int)threadIdx.x;                             \
              int row = ci >> 4, cc = ci & 15;                                  \
              gload16(Kh + base + (size_t)((KT) * 64 + row) * 128               \
                         + ((cc ^ (row & 7)) * 8),                              \
                      &Kls[BUF][(c2 * 512 + w * 64) * 8]);                      \
              int d = ci >> 3, jc = ci & 7;                                     \
              gload16(Vt + vbase + (size_t)(KT) * 8192 + d * 64                 \
                         + ((jc ^ (d & 7)) * 8),                                \
                      &Vls[BUF][(c2 * 512 + w * 64) * 8]);                      \
          } }

    s16x8 qf[4];
    #pragma unroll
    for (int ks = 0; ks < 4; ++ks)
        qf[ks] = *(const s16x8*)(Qh + base + (size_t)(qw + li) * 128 + ks * 32 + g * 8);

    f32x4 acc[8] = {};
    float mrow[4] = { -1e30f, -1e30f, -1e30f, -1e30f };
    float lpart[4] = { 0.f, 0.f, 0.f, 0.f };    // PER-LANE partial of l

    STAGE(0, kt0);
    for (int t = 0; t < 16; ++t) {
        const int cur = t & 1;
        __syncthreads();                  // drains vmcnt: buf[cur] ready
        if (t + 1 < 16) STAGE(cur ^ 1, kt0 + t + 1);   // in flight during compute

        f32x4 st[4];
        __builtin_amdgcn_s_setprio(1);
        #pragma unroll
        for (int nt = 0; nt < 4; ++nt) {
            st[nt] = (f32x4){0.f, 0.f, 0.f, 0.f};
            #pragma unroll
            for (int ks = 0; ks < 4; ++ks) {
                s16x8 bfr = *(const s16x8*)&Kls[cur][(nt * 16 + li) * 128
                                                + (((ks * 4 + g) ^ (li & 7)) * 8)];
                mfma_bf16(&st[nt], qf[ks], bfr);
            }
        }
        __builtin_amdgcn_s_setprio(0);

        // per-LANE max; defer check shuffle-free (log2 domain, THR=8 -> 2^8)
        float mxl[4];
        bool cond = true;
        #pragma unroll
        for (int r = 0; r < 4; ++r) {
            mxl[r] = fmaxf(fmaxf(st[0][r], st[1][r]), fmaxf(st[2][r], st[3][r]));
            cond = cond && (mxl[r] <= mrow[r] + 8.f);
        }
        if (__all(cond)) {
            #pragma unroll
            for (int r = 0; r < 4; ++r) {
                float rs = 0.f;
                #pragma unroll
                for (int nt = 0; nt < 4; ++nt) {
                    float p = exp2f(st[nt][r] - mrow[r]);
                    st[nt][r] = p;
                    rs += p;
                }
                lpart[r] += rs;
            }
        } else {
            #pragma unroll
            for (int r = 0; r < 4; ++r) {
                float mx = mxl[r];
                mx = fmaxf(mx, __shfl_xor(mx, 1));
                mx = fmaxf(mx, __shfl_xor(mx, 2));
                mx = fmaxf(mx, __shfl_xor(mx, 4));
                mx = fmaxf(mx, __shfl_xor(mx, 8));
                float mnew = fmaxf(mrow[r], mx);
                float alpha = exp2f(mrow[r] - mnew);
                float rs = 0.f;
                #pragma unroll
                for (int nt = 0; nt < 4; ++nt) {
                    float p = exp2f(st[nt][r] - mnew);
                    st[nt][r] = p;
                    rs += p;
                }
                lpart[r] = lpart[r] * alpha + rs;   // alpha row-uniform
                mrow[r] = mnew;
                #pragma unroll
                for (int dt = 0; dt < 8; ++dt) acc[dt][r] *= alpha;
            }
        }

        short* pw = Pls[w];
        #pragma unroll
        for (int nt = 0; nt < 4; ++nt)
            #pragma unroll
            for (int r = 0; r < 4; ++r) {
                int row = g * 4 + r;
                pw[row * 64 + (((nt * 2 + (li >> 3)) ^ (row & 7)) * 8) + (li & 7)]
                    = f2bf(st[nt][r]);
            }
        __builtin_amdgcn_s_setprio(1);
        #pragma unroll
        for (int kk = 0; kk < 2; ++kk) {
            s16x8 af = *(const s16x8*)&pw[li * 64 + (((kk * 4 + g) ^ (li & 7)) * 8)];
            #pragma unroll
            for (int dt = 0; dt < 8; ++dt) {
                s16x8 bfr = *(const s16x8*)&Vls[cur][(dt * 16 + li) * 64
                                                + (((kk * 4 + g) ^ (li & 7)) * 8)];
                mfma_bf16(&acc[dt], af, bfr);
            }
        }
        __builtin_amdgcn_s_setprio(0);
    }
    #undef STAGE

    float lrow[4];
    #pragma unroll
    for (int r = 0; r < 4; ++r) {
        float rs = lpart[r];
        rs += __shfl_xor(rs, 1);
        rs += __shfl_xor(rs, 2);
        rs += __shfl_xor(rs, 4);
        rs += __shfl_xor(rs, 8);
        lrow[r] = rs;
    }
    short* __restrict__ Op = half ? O1 : O0;
    float2* __restrict__ mlp = half ? ml1 : ml0;
    #pragma unroll
    for (int r = 0; r < 4; ++r) {
        int row = q0 + w * 16 + g * 4 + r;
        if (li == 0) mlp[hh * 2048 + row] = make_float2(mrow[r], lrow[r]); // m in log2
        #pragma unroll
        for (int dt = 0; dt < 8; ++dt)
            Op[(size_t)row * 1024 + hh * 128 + dt * 16 + li] = f2bf(acc[dt][r]);
    }
}

// ---------------- fused combine + out-proj + residual + LN1 ----------------
// per batch: grid 128 blocks x 256 thr; block owns 16 rows; 4-wave K-split.
// Combine weights in exp2 domain (ml.x is log2-max).
__global__ __launch_bounds__(256) void k_oproj(
    const short* __restrict__ O0, const short* __restrict__ O1,
    const float2* __restrict__ ml0, const float2* __restrict__ ml1,
    const short* __restrict__ WoT, const float* __restrict__ resid,
    const float* __restrict__ gain, float* __restrict__ outp)
{
    __shared__ float red[3][16 * 128];            // 24 KB partial-acc dump
    const int w = threadIdx.x >> 6, lane = threadIdx.x & 63;
    const int g = lane >> 4, li = lane & 15;
    const int m0 = blockIdx.x * 16;
    const int row = m0 + li;
    float w0[2], w1[2], il[2];
    #pragma unroll
    for (int hi = 0; hi < 2; ++hi) {
        int h = w * 2 + hi;
        float2 a = ml0[h * 2048 + row], bml = ml1[h * 2048 + row];
        float M = fmaxf(a.x, bml.x);
        float e0 = exp2f(a.x - M), e1 = exp2f(bml.x - M);
        w0[hi] = e0; w1[hi] = e1;
        il[hi] = 1.f / (a.y * e0 + bml.y * e1);
    }
    f32x4 acc[8] = {};
    #pragma unroll
    for (int kq = 0; kq < 8; ++kq) {
        int ks = w * 8 + kq;
        int hi = kq >> 2;
        s16x8 a0 = *(const s16x8*)(O0 + (size_t)row * 1024 + ks * 32 + g * 8);
        s16x8 a1 = *(const s16x8*)(O1 + (size_t)row * 1024 + ks * 32 + g * 8);
        s16x8 a;
        #pragma unroll
        for (int e = 0; e < 8; ++e)
            a[e] = f2bf((bf2f(a0[e]) * w0[hi] + bf2f(a1[e]) * w1[hi]) * il[hi]);
        #pragma unroll
        for (int nt = 0; nt < 8; ++nt) {
            s16x8 bfr = *(const s16x8*)(WoT + (size_t)(nt * 16 + li) * 1024
                                           + ks * 32 + g * 8);
            mfma_bf16(&acc[nt], a, bfr);
        }
    }
    if (w > 0) {
        #pragma unroll
        for (int nt = 0; nt < 8; ++nt)
            #pragma unroll
            for (int r = 0; r < 4; ++r)
                red[w - 1][(g * 4 + r) * 128 + nt * 16 + li] = acc[nt][r];
    }
    __syncthreads();
    if (w == 0) {
        float gv[8];
        #pragma unroll
        for (int nt = 0; nt < 8; ++nt) gv[nt] = gain[nt * 16 + li];
        #pragma unroll
        for (int r = 0; r < 4; ++r) {
            int orow = m0 + g * 4 + r;
            float s = 0.f, s2 = 0.f;
            #pragma unroll
            for (int nt = 0; nt < 8; ++nt) {
                float v = acc[nt][r]
                        + red[0][(g * 4 + r) * 128 + nt * 16 + li]
                        + red[1][(g * 4 + r) * 128 + nt * 16 + li]
                        + red[2][(g * 4 + r) * 128 + nt * 16 + li]
                        + resid[(size_t)orow * 128 + nt * 16 + li];
                acc[nt][r] = v;
                s += v; s2 += v * v;
            }
            s  += __shfl_xor(s, 1);  s  += __shfl_xor(s, 2);
            s  += __shfl_xor(s, 4);  s  += __shfl_xor(s, 8);
            s2 += __shfl_xor(s2, 1); s2 += __shfl_xor(s2, 2);
            s2 += __shfl_xor(s2, 4); s2 += __shfl_xor(s2, 8);
            float mean = s * (1.f / 128.f);
            float var  = s2 * (1.f / 128.f) - mean * mean;
            float rstd = rsqrtf(var + 1e-5f);
            #pragma unroll
            for (int nt = 0; nt < 8; ++nt)
                outp[(size_t)orow * 128 + nt * 16 + li] =
                    (acc[nt][r] - mean) * rstd * gv[nt];
        }
    }
}

// ---------------- fused FFN (r16 proven 63us version) ----------------------
// ALL batches: grid (64, 4) x 256 thr; block owns 32 rows; 4-wave dff-split.
__global__ __launch_bounds__(256) void k_ffn(
    const float* __restrict__ x1, const short* __restrict__ W1T,
    const short* __restrict__ W2T, const float* __restrict__ gain,
    float* __restrict__ outp)
{
    __shared__ __align__(16) short hls[4][2][16 * 64]; // [wave][mt], swizzled
    __shared__ float red[3][2][16 * 128];              // 48 KB partial-acc dump
    const int w = threadIdx.x >> 6, lane = threadIdx.x & 63;
    const int g = lane >> 4, li = lane & 15;
    const size_t m0 = (size_t)blockIdx.y * 2048 + blockIdx.x * 32;
    s16x8 xf[2][4];
    #pragma unroll
    for (int mt = 0; mt < 2; ++mt)
        #pragma unroll
        for (int ks = 0; ks < 4; ++ks) {
            const float* xr = x1 + (m0 + mt * 16 + li) * 128 + ks * 32 + g * 8;
            float4 v0 = *(const float4*)xr, v1 = *(const float4*)(xr + 4);
            xf[mt][ks] = (s16x8){ f2bf(v0.x), f2bf(v0.y), f2bf(v0.z), f2bf(v0.w),
                                  f2bf(v1.x), f2bf(v1.y), f2bf(v1.z), f2bf(v1.w) };
        }
    f32x4 acc[2][8] = {};
    #pragma unroll 2
    for (int cq = 0; cq < 8; ++cq) {              // ch = w*8 + cq
        int ch = w * 8 + cq;
        f32x4 st[2][4] = {};
        #pragma unroll
        for (int nt = 0; nt < 4; ++nt)
            #pragma unroll
            for (int ks = 0; ks < 4; ++ks) {
                s16x8 bfr = *(const s16x8*)(W1T + (size_t)(ch * 64 + nt * 16 + li) * 128
                                               + ks * 32 + g * 8);
                mfma_bf16(&st[0][nt], xf[0][ks], bfr);
                mfma_bf16(&st[1][nt], xf[1][ks], bfr);
            }
        #pragma unroll
        for (int mt = 0; mt < 2; ++mt) {
            short* hw = hls[w][mt];
            #pragma unroll
            for (int nt = 0; nt < 4; ++nt)
                #pragma unroll
                for (int r = 0; r < 4; ++r) {
                    int rw = g * 4 + r;
                    hw[rw * 64 + (((nt * 2 + (li >> 3)) ^ (rw & 7)) * 8) + (li & 7)]
                        = f2bf(fmaxf(st[mt][nt][r], 0.f));
                }
        }
        #pragma unroll
        for (int kk = 0; kk < 2; ++kk) {
            s16x8 af0 = *(const s16x8*)&hls[w][0][li * 64
                                                  + (((kk * 4 + g) ^ (li & 7)) * 8)];
            s16x8 af1 = *(const s16x8*)&hls[w][1][li * 64
                                                  + (((kk * 4 + g) ^ (li & 7)) * 8)];
            #pragma unroll
            for (int nt = 0; nt < 8; ++nt) {
                s16x8 bfr = *(const s16x8*)(W2T + (size_t)(nt * 16 + li) * 2048
                                               + ch * 64 + kk * 32 + g * 8);
                mfma_bf16(&acc[0][nt], af0, bfr);
                mfma_bf16(&acc[1][nt], af1, bfr);
            }
        }
    }
    if (w > 0) {
        #pragma unroll
        for (int mt = 0; mt < 2; ++mt)
            #pragma unroll
            for (int nt = 0; nt < 8; ++nt)
                #pragma unroll
                for (int r = 0; r < 4; ++r)
                    red[w - 1][mt][(g * 4 + r) * 128 + nt * 16 + li] = acc[mt][nt][r];
    }
    __syncthreads();
    if (w == 0) {
        float gv[8];
        #pragma unroll
        for (int nt = 0; nt < 8; ++nt) gv[nt] = gain[nt * 16 + li];
        #pragma unroll
        for (int mt = 0; mt < 2; ++mt)
            #pragma unroll
            for (int r = 0; r < 4; ++r) {
                size_t orow = m0 + mt * 16 + g * 4 + r;
                float s = 0.f, s2 = 0.f;
                #pragma unroll
                for (int nt = 0; nt < 8; ++nt) {
                    float v = acc[mt][nt][r]
                            + red[0][mt][(g * 4 + r) * 128 + nt * 16 + li]
                            + red[1][mt][(g * 4 + r) * 128 + nt * 16 + li]
                            + red[2][mt][(g * 4 + r) * 128 + nt * 16 + li]
                            + x1[orow * 128 + nt * 16 + li];
                    acc[mt][nt][r] = v;
                    s += v; s2 += v * v;
                }
                s  += __shfl_xor(s, 1);  s  += __shfl_xor(s, 2);
                s  += __shfl_xor(s, 4);  s  += __shfl_xor(s, 8);
                s2 += __shfl_xor(s2, 1); s2 += __shfl_xor(s2, 2);
                s2 += __shfl_xor(s2, 4); s2 += __shfl_xor(s2, 8);
                float mean = s * (1.f / 128.f);
                float var  = s2 * (1.f / 128.f) - mean * mean;
                float rstd = rsqrtf(var + 1e-5f);
                #pragma unroll
                for (int nt = 0; nt < 8; ++nt)
                    outp[orow * 128 + nt * 16 + li] =
                        (acc[mt][nt][r] - mean) * rstd * gv[nt];
            }
    }
}

// ---------------------------------------------------------------------------
extern "C" void kernel_launch(void* const* d_in, const int* in_sizes, int n_in,
                              void* d_out, int out_size, void* d_ws, size_t ws_size,
                              hipStream_t stream)
{
    const float* x  = (const float*)d_in[0];
    const float* Wq = (const float*)d_in[1];
    const float* Wk = (const float*)d_in[2];
    const float* Wv = (const float*)d_in[3];
    const float* Wo = (const float*)d_in[4];
    const float* W1 = (const float*)d_in[5];
    const float* W2 = (const float*)d_in[6];
    const float* g1 = (const float*)d_in[7];
    const float* g2 = (const float*)d_in[8];
    float* out = (float*)d_out;
    (void)in_sizes; (void)n_in; (void)out_size; (void)ws_size;

    char* basep = (char*)d_ws;
    size_t off = 0;
    auto carve = [&](size_t bytes) {
        void* q = basep + off;
        off += (bytes + 255) & ~(size_t)255;
        return q;
    };
    // total ~26.3 MiB (proven green in r18/r19)
    short*  WqT = (short*)carve(1024ull * 128 * 2);
    short*  WkT = (short*)carve(1024ull * 128 * 2);
    short*  WvT = (short*)carve(1024ull * 128 * 2);
    short*  WoT = (short*)carve(128ull * 1024 * 2);
    short*  W1T = (short*)carve(2048ull * 128 * 2);
    short*  W2T = (short*)carve(128ull * 2048 * 2);
    short*  xb  = (short*)carve(8192ull * 128 * 2);       // 2 MiB
    short*  Qh  = (short*)carve(8ull * 2048 * 128 * 2);   // 4 MiB
    short*  Kh  = (short*)carve(8ull * 2048 * 128 * 2);   // 4 MiB
    short*  Vt  = (short*)carve(8ull * 32 * 128 * 64 * 2);// 4 MiB
    short*  O0  = (short*)carve(2048ull * 1024 * 2);      // 4 MiB
    short*  O1  = (short*)carve(2048ull * 1024 * 2);      // 4 MiB
    float2* ml0 = (float2*)carve(8ull * 2048 * 8);
    float2* ml1 = (float2*)carve(8ull * 2048 * 8);

    k_cvt<<<1024, 256, 0, stream>>>(x, xb);
    k_transpose_all<<<4096, 256, 0, stream>>>(Wq, Wk, Wv, Wo, W1, W2,
                                              WqT, WkT, WvT, WoT, W1T, W2T);

    for (int b = 0; b < 4; ++b) {
        const float* xf32 = x + (size_t)b * 2048 * 128;
        float* x1b = out + (size_t)b * 2048 * 128;
        k_qkv<<<dim3(32, 16, 3), 256, 0, stream>>>(xb + (size_t)b * 2048 * 128,
                                                   WqT, WkT, WvT, Qh, Kh, Vt);
        k_attn<<<dim3(16, 8, 2), 512, 0, stream>>>(Qh, Kh, Vt, O0, O1, ml0, ml1);
        k_oproj<<<128, 256, 0, stream>>>(O0, O1, ml0, ml1, WoT, xf32, g1, x1b);
    }

    k_ffn<<<dim3(64, 4), 256, 0, stream>>>(out, W1T, W2T, g2, out);
}

// Round 22
// 285.049 us; speedup vs baseline: 1.2894x; 1.2530x over previous
//
#include <hip/hip_runtime.h>
#include <stdint.h>

// ---------------------------------------------------------------------------
// TransformerEncoderLayer: b=4 s=2048 d=128 h=8 (head_dim=128) dff=2048
// Round-22: structural consolidation (r21 counters: everything latency-bound,
// launch-count dominated).
//  - batch-PAIR stage A: one qkv/attn/oproj launch per 2 batches -> 8 launches
//  - kv-split removed: attn does all 32 tiles, normalizes, writes ONE O;
//    oproj loses combine + ml entirely (direct bf16 A-frags).
//  - ws 34.3 MiB (green 30.6 proven; fail located ~45).
// Kernel internals (swizzles, exp2 softmax, defer-max, dbuf) = r21 (green).
// ---------------------------------------------------------------------------

using f32x4 = __attribute__((ext_vector_type(4))) float;
using s16x8 = __attribute__((ext_vector_type(8))) short;
using s16x4 = __attribute__((ext_vector_type(4))) short;
typedef __bf16 bf16x8 __attribute__((ext_vector_type(8)));

__device__ inline void mfma_bf16(f32x4* acc, s16x8 a, s16x8 b) {
    *acc = __builtin_amdgcn_mfma_f32_16x16x32_bf16(
        __builtin_bit_cast(bf16x8, a), __builtin_bit_cast(bf16x8, b), *acc, 0, 0, 0);
}

__device__ inline short f2bf(float f) {   // RNE f32 -> bf16 bits
    uint32_t u = __builtin_bit_cast(uint32_t, f);
    u += 0x7fffu + ((u >> 16) & 1u);
    return (short)(u >> 16);
}

__device__ inline float bf2f(short s) {
    return __builtin_bit_cast(float, (uint32_t)((uint16_t)s) << 16);
}

// async global->LDS, 16B per lane; LDS dest = wave-uniform base + lane*16
__device__ inline void gload16(const short* g, short* l) {
    __builtin_amdgcn_global_load_lds(
        (const __attribute__((address_space(1))) void*)g,
        (__attribute__((address_space(3))) void*)l, 16, 0, 0);
}

// ---------------- ALL weight transposes, one launch ------------------------
__global__ __launch_bounds__(256) void k_transpose_all(
    const float* __restrict__ Wq, const float* __restrict__ Wk,
    const float* __restrict__ Wv, const float* __restrict__ Wo,
    const float* __restrict__ W1, const float* __restrict__ W2,
    short* __restrict__ WqT, short* __restrict__ WkT, short* __restrict__ WvT,
    short* __restrict__ WoT, short* __restrict__ W1T, short* __restrict__ W2T)
{
    int b = blockIdx.x;
    const float* w; short* wt; int R, lc, lb;
    if (b < 512)       { w = Wq; wt = WqT; R = 128;  lc = 10; lb = 0;    }
    else if (b < 1024) { w = Wk; wt = WkT; R = 128;  lc = 10; lb = 512;  }
    else if (b < 1536) { w = Wv; wt = WvT; R = 128;  lc = 10; lb = 1024; }
    else if (b < 2048) { w = Wo; wt = WoT; R = 1024; lc = 7;  lb = 1536; }
    else if (b < 3072) { w = W1; wt = W1T; R = 128;  lc = 11; lb = 2048; }
    else               { w = W2; wt = W2T; R = 2048; lc = 7;  lb = 3072; }
    int i = (b - lb) * 256 + threadIdx.x;
    int r = i >> lc, c = i & ((1 << lc) - 1);
    wt[c * R + r] = f2bf(w[i]);
}

// ---------------- QKV projection (one PAIR of batches, 8 heads each) -------
// grid (32, 32, 3): y -> batch-in-pair (y>>4) and n-block (y&15).
// Q pre-scaled by log2(e)/sqrt(d). Layouts: Q,K [bh16][2048][128];
// V tile-blocked [bh16][kt32][d128][s64].
__global__ __launch_bounds__(256) void k_qkv(
    const float* __restrict__ xPair, const short* __restrict__ WqT,
    const short* __restrict__ WkT, const short* __restrict__ WvT,
    short* __restrict__ Qh, short* __restrict__ Kh, short* __restrict__ Vt)
{
    __shared__ __align__(16) short Bls[64 * 128];   // swizzled [col][k]
    const int z = blockIdx.z;
    const int bt = blockIdx.y >> 4;               // batch in pair
    const int n0 = (blockIdx.y & 15) * 64;        // 0..960
    const short* __restrict__ WT = (z == 0) ? WqT : (z == 1) ? WkT : WvT; // [1024][128]
    const int w = threadIdx.x >> 6, lane = threadIdx.x & 63;
    const int g = lane >> 4, li = lane & 15;
    const int m0 = blockIdx.x * 64 + w * 16;
    const float* __restrict__ xB = xPair + (size_t)bt * 2048 * 128;

    #pragma unroll
    for (int c2 = 0; c2 < 4; ++c2) {
        int ci = c2 * 256 + (int)threadIdx.x;
        int row = ci >> 4, cc = ci & 15;
        gload16(WT + (size_t)(n0 + row) * 128 + ((cc ^ (row & 7)) * 8),
                &Bls[(c2 * 256 + w * 64) * 8]);
    }
    __syncthreads();

    f32x4 acc[4] = {};
    #pragma unroll
    for (int ks = 0; ks < 4; ++ks) {
        const float* xr = xB + (size_t)(m0 + li) * 128 + ks * 32 + g * 8;
        float4 v0 = *(const float4*)xr, v1 = *(const float4*)(xr + 4);
        s16x8 a = { f2bf(v0.x), f2bf(v0.y), f2bf(v0.z), f2bf(v0.w),
                    f2bf(v1.x), f2bf(v1.y), f2bf(v1.z), f2bf(v1.w) };
        #pragma unroll
        for (int nt = 0; nt < 4; ++nt) {
            s16x8 bfr = *(const s16x8*)&Bls[(nt * 16 + li) * 128
                                            + (((ks * 4 + g) ^ (li & 7)) * 8)];
            mfma_bf16(&acc[nt], a, bfr);
        }
    }
    // 1/sqrt(128) * log2(e): scores land in log2 domain
    const float sc = (z == 0) ? 0.12751879524622257f : 1.0f;
    #pragma unroll
    for (int nt = 0; nt < 4; ++nt) {
        int col = n0 + nt * 16 + li;              // 0..1023
        int hh = col >> 7, dd = col & 127;        // head, dim
        int bh = bt * 8 + hh;
        if (z == 2) {
            int row0 = m0 + g * 4;                // s, multiple of 4
            int kt = row0 >> 6, so = row0 & 63;
            s16x4 o = { f2bf(acc[nt][0]), f2bf(acc[nt][1]),
                        f2bf(acc[nt][2]), f2bf(acc[nt][3]) };
            *(s16x4*)(Vt + (((size_t)bh * 32 + kt) * 128 + dd) * 64 + so) = o;
        } else {
            short* __restrict__ dst = (z == 0) ? Qh : Kh;
            #pragma unroll
            for (int r = 0; r < 4; ++r)
                dst[((size_t)bh * 2048 + m0 + g * 4 + r) * 128 + dd] =
                    f2bf(acc[nt][r] * sc);
        }
    }
}

// ---------------- flash attention, 8 waves (QBLK=128), full kv range -------
// grid (16 qblocks, 8 heads, 2 batches) = 256 blocks x 512 thr. All 32 kv
// tiles per block; normalized O written directly (no split, no ml).
__global__ __launch_bounds__(512) void k_attn(
    const short* __restrict__ Qh, const short* __restrict__ Kh,
    const short* __restrict__ Vt, short* __restrict__ O)
{
    __shared__ __align__(16) short Kls[2][64 * 128];   // swizzled [k][d], dbuf
    __shared__ __align__(16) short Vls[2][128 * 64];   // swizzled [d][k], dbuf
    __shared__ __align__(16) short Pls[8][16 * 64];    // per-wave swizzled [q][k]
    const int hh = blockIdx.y;
    const int bt = blockIdx.z;                         // batch in pair
    const int bh = bt * 8 + hh;
    const size_t base  = (size_t)bh * 2048 * 128;
    const size_t vbase = (size_t)bh * 32 * 8192;       // tile-blocked V^T
    const int w = threadIdx.x >> 6, lane = threadIdx.x & 63;
    const int g = lane >> 4, li = lane & 15;
    const int q0 = blockIdx.x * 128;
    const int qw = q0 + w * 16;

    #define STAGE(BUF, KT)                                                      \
        { _Pragma("unroll")                                                     \
          for (int c2 = 0; c2 < 2; ++c2) {                                      \
              int ci = c2 * 512 + (int)threadIdx.x;                             \
              int row = ci >> 4, cc = ci & 15;                                  \
              gload16(Kh + base + (size_t)((KT) * 64 + row) * 128               \
                         + ((cc ^ (row & 7)) * 8),                              \
                      &Kls[BUF][(c2 * 512 + w * 64) * 8]);                      \
              int d = ci >> 3, jc = ci & 7;                                     \
              gload16(Vt + vbase + (size_t)(KT) * 8192 + d * 64                 \
                         + ((jc ^ (d & 7)) * 8),                                \
                      &Vls[BUF][(c2 * 512 + w * 64) * 8]);                      \
          } }

    s16x8 qf[4];
    #pragma unroll
    for (int ks = 0; ks < 4; ++ks)
        qf[ks] = *(const s16x8*)(Qh + base + (size_t)(qw + li) * 128 + ks * 32 + g * 8);

    f32x4 acc[8] = {};
    float mrow[4] = { -1e30f, -1e30f, -1e30f, -1e30f };
    float lpart[4] = { 0.f, 0.f, 0.f, 0.f };    // PER-LANE partial of l

    STAGE(0, 0);
    for (int t = 0; t < 32; ++t) {
        const int cur = t & 1;
        __syncthreads();                  // drains vmcnt: buf[cur] ready
        if (t + 1 < 32) STAGE(cur ^ 1, t + 1);   // in flight during compute

        f32x4 st[4];
        __builtin_amdgcn_s_setprio(1);
        #pragma unroll
        for (int nt = 0; nt < 4; ++nt) {
            st[nt] = (f32x4){0.f, 0.f, 0.f, 0.f};
            #pragma unroll
            for (int ks = 0; ks < 4; ++ks) {
                s16x8 bfr = *(const s16x8*)&Kls[cur][(nt * 16 + li) * 128
                                                + (((ks * 4 + g) ^ (li & 7)) * 8)];
                mfma_bf16(&st[nt], qf[ks], bfr);
            }
        }
        __builtin_amdgcn_s_setprio(0);

        // per-LANE max; shuffle-free defer check (log2 domain, THR=8)
        float mxl[4];
        bool cond = true;
        #pragma unroll
        for (int r = 0; r < 4; ++r) {
            mxl[r] = fmaxf(fmaxf(st[0][r], st[1][r]), fmaxf(st[2][r], st[3][r]));
            cond = cond && (mxl[r] <= mrow[r] + 8.f);
        }
        if (__all(cond)) {
            #pragma unroll
            for (int r = 0; r < 4; ++r) {
                float rs = 0.f;
                #pragma unroll
                for (int nt = 0; nt < 4; ++nt) {
                    float p = exp2f(st[nt][r] - mrow[r]);
                    st[nt][r] = p;
                    rs += p;
                }
                lpart[r] += rs;
            }
        } else {
            #pragma unroll
            for (int r = 0; r < 4; ++r) {
                float mx = mxl[r];
                mx = fmaxf(mx, __shfl_xor(mx, 1));
                mx = fmaxf(mx, __shfl_xor(mx, 2));
                mx = fmaxf(mx, __shfl_xor(mx, 4));
                mx = fmaxf(mx, __shfl_xor(mx, 8));
                float mnew = fmaxf(mrow[r], mx);
                float alpha = exp2f(mrow[r] - mnew);
                float rs = 0.f;
                #pragma unroll
                for (int nt = 0; nt < 4; ++nt) {
                    float p = exp2f(st[nt][r] - mnew);
                    st[nt][r] = p;
                    rs += p;
                }
                lpart[r] = lpart[r] * alpha + rs;   // alpha row-uniform
                mrow[r] = mnew;
                #pragma unroll
                for (int dt = 0; dt < 8; ++dt) acc[dt][r] *= alpha;
            }
        }

        short* pw = Pls[w];
        #pragma unroll
        for (int nt = 0; nt < 4; ++nt)
            #pragma unroll
            for (int r = 0; r < 4; ++r) {
                int row = g * 4 + r;
                pw[row * 64 + (((nt * 2 + (li >> 3)) ^ (row & 7)) * 8) + (li & 7)]
                    = f2bf(st[nt][r]);
            }
        __builtin_amdgcn_s_setprio(1);
        #pragma unroll
        for (int kk = 0; kk < 2; ++kk) {
            s16x8 af = *(const s16x8*)&pw[li * 64 + (((kk * 4 + g) ^ (li & 7)) * 8)];
            #pragma unroll
            for (int dt = 0; dt < 8; ++dt) {
                s16x8 bfr = *(const s16x8*)&Vls[cur][(dt * 16 + li) * 64
                                                + (((kk * 4 + g) ^ (li & 7)) * 8)];
                mfma_bf16(&acc[dt], af, bfr);
            }
        }
        __builtin_amdgcn_s_setprio(0);
    }
    #undef STAGE

    // epilogue: reduce l, normalize, write O (seq-major [2*2048][1024])
    #pragma unroll
    for (int r = 0; r < 4; ++r) {
        float rs = lpart[r];
        rs += __shfl_xor(rs, 1);
        rs += __shfl_xor(rs, 2);
        rs += __shfl_xor(rs, 4);
        rs += __shfl_xor(rs, 8);
        float inv = 1.f / rs;
        size_t row = (size_t)bt * 2048 + q0 + w * 16 + g * 4 + r;
        #pragma unroll
        for (int dt = 0; dt < 8; ++dt)
            O[row * 1024 + hh * 128 + dt * 16 + li] = f2bf(acc[dt][r] * inv);
    }
}

// ---------------- fused out-proj + residual + LN1 (one PAIR) ---------------
// grid 256 blocks x 256 thr; block owns 16 rows of the 4096-row pair;
// 4-wave K-split over the 32 ks steps; LDS dump reduce; direct bf16 A-frags.
__global__ __launch_bounds__(256) void k_oproj(
    const short* __restrict__ O, const short* __restrict__ WoT,
    const float* __restrict__ resid, const float* __restrict__ gain,
    float* __restrict__ outp)
{
    __shared__ float red[3][16 * 128];            // 24 KB partial-acc dump
    const int w = threadIdx.x >> 6, lane = threadIdx.x & 63;
    const int g = lane >> 4, li = lane & 15;
    const int m0 = blockIdx.x * 16;               // 0..4080
    const int row = m0 + li;
    f32x4 acc[8] = {};
    #pragma unroll
    for (int kq = 0; kq < 8; ++kq) {              // ks = w*8 + kq
        int ks = w * 8 + kq;
        s16x8 a = *(const s16x8*)(O + (size_t)row * 1024 + ks * 32 + g * 8);
        #pragma unroll
        for (int nt = 0; nt < 8; ++nt) {
            s16x8 bfr = *(const s16x8*)(WoT + (size_t)(nt * 16 + li) * 1024
                                           + ks * 32 + g * 8);
            mfma_bf16(&acc[nt], a, bfr);
        }
    }
    if (w > 0) {
        #pragma unroll
        for (int nt = 0; nt < 8; ++nt)
            #pragma unroll
            for (int r = 0; r < 4; ++r)
                red[w - 1][(g * 4 + r) * 128 + nt * 16 + li] = acc[nt][r];
    }
    __syncthreads();
    if (w == 0) {
        float gv[8];
        #pragma unroll
        for (int nt = 0; nt < 8; ++nt) gv[nt] = gain[nt * 16 + li];
        #pragma unroll
        for (int r = 0; r < 4; ++r) {
            int orow = m0 + g * 4 + r;
            float s = 0.f, s2 = 0.f;
            #pragma unroll
            for (int nt = 0; nt < 8; ++nt) {
                float v = acc[nt][r]
                        + red[0][(g * 4 + r) * 128 + nt * 16 + li]
                        + red[1][(g * 4 + r) * 128 + nt * 16 + li]
                        + red[2][(g * 4 + r) * 128 + nt * 16 + li]
                        + resid[(size_t)orow * 128 + nt * 16 + li];
                acc[nt][r] = v;
                s += v; s2 += v * v;
            }
            s  += __shfl_xor(s, 1);  s  += __shfl_xor(s, 2);
            s  += __shfl_xor(s, 4);  s  += __shfl_xor(s, 8);
            s2 += __shfl_xor(s2, 1); s2 += __shfl_xor(s2, 2);
            s2 += __shfl_xor(s2, 4); s2 += __shfl_xor(s2, 8);
            float mean = s * (1.f / 128.f);
            float var  = s2 * (1.f / 128.f) - mean * mean;
            float rstd = rsqrtf(var + 1e-5f);
            #pragma unroll
            for (int nt = 0; nt < 8; ++nt)
                outp[(size_t)orow * 128 + nt * 16 + li] =
                    (acc[nt][r] - mean) * rstd * gv[nt];
        }
    }
}

// ---------------- fused FFN (r16 proven 63us version) ----------------------
__global__ __launch_bounds__(256) void k_ffn(
    const float* __restrict__ x1, const short* __restrict__ W1T,
    const short* __restrict__ W2T, const float* __restrict__ gain,
    float* __restrict__ outp)
{
    __shared__ __align__(16) short hls[4][2][16 * 64]; // [wave][mt], swizzled
    __shared__ float red[3][2][16 * 128];              // 48 KB partial-acc dump
    const int w = threadIdx.x >> 6, lane = threadIdx.x & 63;
    const int g = lane >> 4, li = lane & 15;
    const size_t m0 = (size_t)blockIdx.y * 2048 + blockIdx.x * 32;
    s16x8 xf[2][4];
    #pragma unroll
    for (int mt = 0; mt < 2; ++mt)
        #pragma unroll
        for (int ks = 0; ks < 4; ++ks) {
            const float* xr = x1 + (m0 + mt * 16 + li) * 128 + ks * 32 + g * 8;
            float4 v0 = *(const float4*)xr, v1 = *(const float4*)(xr + 4);
            xf[mt][ks] = (s16x8){ f2bf(v0.x), f2bf(v0.y), f2bf(v0.z), f2bf(v0.w),
                                  f2bf(v1.x), f2bf(v1.y), f2bf(v1.z), f2bf(v1.w) };
        }
    f32x4 acc[2][8] = {};
    #pragma unroll 2
    for (int cq = 0; cq < 8; ++cq) {              // ch = w*8 + cq
        int ch = w * 8 + cq;
        f32x4 st[2][4] = {};
        #pragma unroll
        for (int nt = 0; nt < 4; ++nt)
            #pragma unroll
            for (int ks = 0; ks < 4; ++ks) {
                s16x8 bfr = *(const s16x8*)(W1T + (size_t)(ch * 64 + nt * 16 + li) * 128
                                               + ks * 32 + g * 8);
                mfma_bf16(&st[0][nt], xf[0][ks], bfr);
                mfma_bf16(&st[1][nt], xf[1][ks], bfr);
            }
        #pragma unroll
        for (int mt = 0; mt < 2; ++mt) {
            short* hw = hls[w][mt];
            #pragma unroll
            for (int nt = 0; nt < 4; ++nt)
                #pragma unroll
                for (int r = 0; r < 4; ++r) {
                    int rw = g * 4 + r;
                    hw[rw * 64 + (((nt * 2 + (li >> 3)) ^ (rw & 7)) * 8) + (li & 7)]
                        = f2bf(fmaxf(st[mt][nt][r], 0.f));
                }
        }
        #pragma unroll
        for (int kk = 0; kk < 2; ++kk) {
            s16x8 af0 = *(const s16x8*)&hls[w][0][li * 64
                                                  + (((kk * 4 + g) ^ (li & 7)) * 8)];
            s16x8 af1 = *(const s16x8*)&hls[w][1][li * 64
                                                  + (((kk * 4 + g) ^ (li & 7)) * 8)];
            #pragma unroll
            for (int nt = 0; nt < 8; ++nt) {
                s16x8 bfr = *(const s16x8*)(W2T + (size_t)(nt * 16 + li) * 2048
                                               + ch * 64 + kk * 32 + g * 8);
                mfma_bf16(&acc[0][nt], af0, bfr);
                mfma_bf16(&acc[1][nt], af1, bfr);
            }
        }
    }
    if (w > 0) {
        #pragma unroll
        for (int mt = 0; mt < 2; ++mt)
            #pragma unroll
            for (int nt = 0; nt < 8; ++nt)
                #pragma unroll
                for (int r = 0; r < 4; ++r)
                    red[w - 1][mt][(g * 4 + r) * 128 + nt * 16 + li] = acc[mt][nt][r];
    }
    __syncthreads();
    if (w == 0) {
        float gv[8];
        #pragma unroll
        for (int nt = 0; nt < 8; ++nt) gv[nt] = gain[nt * 16 + li];
        #pragma unroll
        for (int mt = 0; mt < 2; ++mt)
            #pragma unroll
            for (int r = 0; r < 4; ++r) {
                size_t orow = m0 + mt * 16 + g * 4 + r;
                float s = 0.f, s2 = 0.f;
                #pragma unroll
                for (int nt = 0; nt < 8; ++nt) {
                    float v = acc[mt][nt][r]
                            + red[0][mt][(g * 4 + r) * 128 + nt * 16 + li]
                            + red[1][mt][(g * 4 + r) * 128 + nt * 16 + li]
                            + red[2][mt][(g * 4 + r) * 128 + nt * 16 + li]
                            + x1[orow * 128 + nt * 16 + li];
                    acc[mt][nt][r] = v;
                    s += v; s2 += v * v;
                }
                s  += __shfl_xor(s, 1);  s  += __shfl_xor(s, 2);
                s  += __shfl_xor(s, 4);  s  += __shfl_xor(s, 8);
                s2 += __shfl_xor(s2, 1); s2 += __shfl_xor(s2, 2);
                s2 += __shfl_xor(s2, 4); s2 += __shfl_xor(s2, 8);
                float mean = s * (1.f / 128.f);
                float var  = s2 * (1.f / 128.f) - mean * mean;
                float rstd = rsqrtf(var + 1e-5f);
                #pragma unroll
                for (int nt = 0; nt < 8; ++nt)
                    outp[orow * 128 + nt * 16 + li] =
                        (acc[mt][nt][r] - mean) * rstd * gv[nt];
            }
    }
}

// ---------------------------------------------------------------------------
extern "C" void kernel_launch(void* const* d_in, const int* in_sizes, int n_in,
                              void* d_out, int out_size, void* d_ws, size_t ws_size,
                              hipStream_t stream)
{
    const float* x  = (const float*)d_in[0];
    const float* Wq = (const float*)d_in[1];
    const float* Wk = (const float*)d_in[2];
    const float* Wv = (const float*)d_in[3];
    const float* Wo = (const float*)d_in[4];
    const float* W1 = (const float*)d_in[5];
    const float* W2 = (const float*)d_in[6];
    const float* g1 = (const float*)d_in[7];
    const float* g2 = (const float*)d_in[8];
    float* out = (float*)d_out;
    (void)in_sizes; (void)n_in; (void)out_size; (void)ws_size;

    char* basep = (char*)d_ws;
    size_t off = 0;
    auto carve = [&](size_t bytes) {
        void* q = basep + off;
        off += (bytes + 255) & ~(size_t)255;
        return q;
    };
    // total ~34.3 MiB (green proven 30.6; fail located ~45)
    short*  WqT = (short*)carve(1024ull * 128 * 2);
    short*  WkT = (short*)carve(1024ull * 128 * 2);
    short*  WvT = (short*)carve(1024ull * 128 * 2);
    short*  WoT = (short*)carve(128ull * 1024 * 2);
    short*  W1T = (short*)carve(2048ull * 128 * 2);
    short*  W2T = (short*)carve(128ull * 2048 * 2);
    short*  Qh  = (short*)carve(16ull * 2048 * 128 * 2);   // 8 MiB (pair)
    short*  Kh  = (short*)carve(16ull * 2048 * 128 * 2);   // 8 MiB
    short*  Vt  = (short*)carve(16ull * 32 * 128 * 64 * 2);// 8 MiB
    short*  O   = (short*)carve(4096ull * 1024 * 2);       // 8 MiB (pair)

    k_transpose_all<<<4096, 256, 0, stream>>>(Wq, Wk, Wv, Wo, W1, W2,
                                              WqT, WkT, WvT, WoT, W1T, W2T);

    for (int p = 0; p < 2; ++p) {
        const float* xp = x + (size_t)p * 4096 * 128;
        float* outp = out + (size_t)p * 4096 * 128;
        k_qkv<<<dim3(32, 32, 3), 256, 0, stream>>>(xp, WqT, WkT, WvT,
                                                   Qh, Kh, Vt);
        k_attn<<<dim3(16, 8, 2), 512, 0, stream>>>(Qh, Kh, Vt, O);
        k_oproj<<<256, 256, 0, stream>>>(O, WoT, xp, g1, outp);
    }

    k_ffn<<<dim3(64, 4), 256, 0, stream>>>(out, W1T, W2T, g2, out);
}

// Round 23
// 275.704 us; speedup vs baseline: 1.3331x; 1.0339x over previous
//
#include <hip/hip_runtime.h>
#include <stdint.h>

// ---------------------------------------------------------------------------
// TransformerEncoderLayer: b=4 s=2048 d=128 h=8 (head_dim=128) dff=2048
// Round-23 (r22 green at 285us; attn VALU-chain bound: VALUBusy 37.7 vs
// MfmaUtil 16.9). Three algebraically-neutral VALU cuts in k_attn:
//  1. st C-init = -mrow  -> kills 16 subs/tile; defer check becomes mxl<=8
//  2. l via ones-MFMA    -> kills rs accumulation + epilogue shuffle reduce
//  3. native __bf16 casts for P/O stores (cvt_pk pairing)
// Everything else byte-identical to r22.
// ---------------------------------------------------------------------------

using f32x4 = __attribute__((ext_vector_type(4))) float;
using s16x8 = __attribute__((ext_vector_type(8))) short;
using s16x4 = __attribute__((ext_vector_type(4))) short;
typedef __bf16 bf16x8 __attribute__((ext_vector_type(8)));

__device__ inline void mfma_bf16(f32x4* acc, s16x8 a, s16x8 b) {
    *acc = __builtin_amdgcn_mfma_f32_16x16x32_bf16(
        __builtin_bit_cast(bf16x8, a), __builtin_bit_cast(bf16x8, b), *acc, 0, 0, 0);
}

__device__ inline short f2bf(float f) {   // RNE f32 -> bf16 bits (prep paths)
    uint32_t u = __builtin_bit_cast(uint32_t, f);
    u += 0x7fffu + ((u >> 16) & 1u);
    return (short)(u >> 16);
}

__device__ inline short f2bf_hw(float f) { // native cast (cvt_pk pairable)
    return __builtin_bit_cast(short, (__bf16)f);
}

__device__ inline float bf2f(short s) {
    return __builtin_bit_cast(float, (uint32_t)((uint16_t)s) << 16);
}

// async global->LDS, 16B per lane; LDS dest = wave-uniform base + lane*16
__device__ inline void gload16(const short* g, short* l) {
    __builtin_amdgcn_global_load_lds(
        (const __attribute__((address_space(1))) void*)g,
        (__attribute__((address_space(3))) void*)l, 16, 0, 0);
}

// ---------------- ALL weight transposes, one launch ------------------------
__global__ __launch_bounds__(256) void k_transpose_all(
    const float* __restrict__ Wq, const float* __restrict__ Wk,
    const float* __restrict__ Wv, const float* __restrict__ Wo,
    const float* __restrict__ W1, const float* __restrict__ W2,
    short* __restrict__ WqT, short* __restrict__ WkT, short* __restrict__ WvT,
    short* __restrict__ WoT, short* __restrict__ W1T, short* __restrict__ W2T)
{
    int b = blockIdx.x;
    const float* w; short* wt; int R, lc, lb;
    if (b < 512)       { w = Wq; wt = WqT; R = 128;  lc = 10; lb = 0;    }
    else if (b < 1024) { w = Wk; wt = WkT; R = 128;  lc = 10; lb = 512;  }
    else if (b < 1536) { w = Wv; wt = WvT; R = 128;  lc = 10; lb = 1024; }
    else if (b < 2048) { w = Wo; wt = WoT; R = 1024; lc = 7;  lb = 1536; }
    else if (b < 3072) { w = W1; wt = W1T; R = 128;  lc = 11; lb = 2048; }
    else               { w = W2; wt = W2T; R = 2048; lc = 7;  lb = 3072; }
    int i = (b - lb) * 256 + threadIdx.x;
    int r = i >> lc, c = i & ((1 << lc) - 1);
    wt[c * R + r] = f2bf(w[i]);
}

// ---------------- QKV projection (one PAIR of batches, 8 heads each) -------
__global__ __launch_bounds__(256) void k_qkv(
    const float* __restrict__ xPair, const short* __restrict__ WqT,
    const short* __restrict__ WkT, const short* __restrict__ WvT,
    short* __restrict__ Qh, short* __restrict__ Kh, short* __restrict__ Vt)
{
    __shared__ __align__(16) short Bls[64 * 128];   // swizzled [col][k]
    const int z = blockIdx.z;
    const int bt = blockIdx.y >> 4;               // batch in pair
    const int n0 = (blockIdx.y & 15) * 64;        // 0..960
    const short* __restrict__ WT = (z == 0) ? WqT : (z == 1) ? WkT : WvT; // [1024][128]
    const int w = threadIdx.x >> 6, lane = threadIdx.x & 63;
    const int g = lane >> 4, li = lane & 15;
    const int m0 = blockIdx.x * 64 + w * 16;
    const float* __restrict__ xB = xPair + (size_t)bt * 2048 * 128;

    #pragma unroll
    for (int c2 = 0; c2 < 4; ++c2) {
        int ci = c2 * 256 + (int)threadIdx.x;
        int row = ci >> 4, cc = ci & 15;
        gload16(WT + (size_t)(n0 + row) * 128 + ((cc ^ (row & 7)) * 8),
                &Bls[(c2 * 256 + w * 64) * 8]);
    }
    __syncthreads();

    f32x4 acc[4] = {};
    #pragma unroll
    for (int ks = 0; ks < 4; ++ks) {
        const float* xr = xB + (size_t)(m0 + li) * 128 + ks * 32 + g * 8;
        float4 v0 = *(const float4*)xr, v1 = *(const float4*)(xr + 4);
        s16x8 a = { f2bf(v0.x), f2bf(v0.y), f2bf(v0.z), f2bf(v0.w),
                    f2bf(v1.x), f2bf(v1.y), f2bf(v1.z), f2bf(v1.w) };
        #pragma unroll
        for (int nt = 0; nt < 4; ++nt) {
            s16x8 bfr = *(const s16x8*)&Bls[(nt * 16 + li) * 128
                                            + (((ks * 4 + g) ^ (li & 7)) * 8)];
            mfma_bf16(&acc[nt], a, bfr);
        }
    }
    // 1/sqrt(128) * log2(e): scores land in log2 domain
    const float sc = (z == 0) ? 0.12751879524622257f : 1.0f;
    #pragma unroll
    for (int nt = 0; nt < 4; ++nt) {
        int col = n0 + nt * 16 + li;              // 0..1023
        int hh = col >> 7, dd = col & 127;        // head, dim
        int bh = bt * 8 + hh;
        if (z == 2) {
            int row0 = m0 + g * 4;                // s, multiple of 4
            int kt = row0 >> 6, so = row0 & 63;
            s16x4 o = { f2bf(acc[nt][0]), f2bf(acc[nt][1]),
                        f2bf(acc[nt][2]), f2bf(acc[nt][3]) };
            *(s16x4*)(Vt + (((size_t)bh * 32 + kt) * 128 + dd) * 64 + so) = o;
        } else {
            short* __restrict__ dst = (z == 0) ? Qh : Kh;
            #pragma unroll
            for (int r = 0; r < 4; ++r)
                dst[((size_t)bh * 2048 + m0 + g * 4 + r) * 128 + dd] =
                    f2bf(acc[nt][r] * sc);
        }
    }
}

// ---------------- flash attention, 8 waves (QBLK=128), full kv range -------
// grid (16 qblocks, 8 heads, 2 batches) = 256 blocks x 512 thr.
// st pre-shifted by -mrow at MFMA C-init; l via ones-MFMA.
__global__ __launch_bounds__(512) void k_attn(
    const short* __restrict__ Qh, const short* __restrict__ Kh,
    const short* __restrict__ Vt, short* __restrict__ O)
{
    __shared__ __align__(16) short Kls[2][64 * 128];   // swizzled [k][d], dbuf
    __shared__ __align__(16) short Vls[2][128 * 64];   // swizzled [d][k], dbuf
    __shared__ __align__(16) short Pls[8][16 * 64];    // per-wave swizzled [q][k]
    const int hh = blockIdx.y;
    const int bt = blockIdx.z;
    const int bh = bt * 8 + hh;
    const size_t base  = (size_t)bh * 2048 * 128;
    const size_t vbase = (size_t)bh * 32 * 8192;       // tile-blocked V^T
    const int w = threadIdx.x >> 6, lane = threadIdx.x & 63;
    const int g = lane >> 4, li = lane & 15;
    const int q0 = blockIdx.x * 128;
    const int qw = q0 + w * 16;

    #define STAGE(BUF, KT)                                                      \
        { _Pragma("unroll")                                                     \
          for (int c2 = 0; c2 < 2; ++c2) {                                      \
              int ci = c2 * 512 + (int)threadIdx.x;                             \
              int row = ci >> 4, cc = ci & 15;                                  \
              gload16(Kh + base + (size_t)((KT) * 64 + row) * 128               \
                         + ((cc ^ (row & 7)) * 8),                              \
                      &Kls[BUF][(c2 * 512 + w * 64) * 8]);                      \
              int d = ci >> 3, jc = ci & 7;                                     \
              gload16(Vt + vbase + (size_t)(KT) * 8192 + d * 64                 \
                         + ((jc ^ (d & 7)) * 8),                                \
                      &Vls[BUF][(c2 * 512 + w * 64) * 8]);                      \
          } }

    s16x8 qf[4];
    #pragma unroll
    for (int ks = 0; ks < 4; ++ks)
        qf[ks] = *(const s16x8*)(Qh + base + (size_t)(qw + li) * 128 + ks * 32 + g * 8);

    const s16x8 ones = { 0x3F80, 0x3F80, 0x3F80, 0x3F80,
                         0x3F80, 0x3F80, 0x3F80, 0x3F80 };  // bf16(1.0) x8

    f32x4 acc[8] = {};
    f32x4 acc_l = { 0.f, 0.f, 0.f, 0.f };       // l via ones-MFMA
    float mrow[4] = { -1e30f, -1e30f, -1e30f, -1e30f };

    STAGE(0, 0);
    for (int t = 0; t < 32; ++t) {
        const int cur = t & 1;
        __syncthreads();                  // drains vmcnt: buf[cur] ready
        if (t + 1 < 32) STAGE(cur ^ 1, t + 1);   // in flight during compute

        // st initialized to -mrow: QK^T lands pre-shifted (saves 16 subs)
        f32x4 nm = { -mrow[0], -mrow[1], -mrow[2], -mrow[3] };
        f32x4 st[4] = { nm, nm, nm, nm };
        __builtin_amdgcn_s_setprio(1);
        #pragma unroll
        for (int nt = 0; nt < 4; ++nt)
            #pragma unroll
            for (int ks = 0; ks < 4; ++ks) {
                s16x8 bfr = *(const s16x8*)&Kls[cur][(nt * 16 + li) * 128
                                                + (((ks * 4 + g) ^ (li & 7)) * 8)];
                mfma_bf16(&st[nt], qf[ks], bfr);
            }
        __builtin_amdgcn_s_setprio(0);

        // per-LANE max of shifted scores; defer check = mxl <= 8
        float mxl[4];
        bool cond = true;
        #pragma unroll
        for (int r = 0; r < 4; ++r) {
            mxl[r] = fmaxf(fmaxf(st[0][r], st[1][r]), fmaxf(st[2][r], st[3][r]));
            cond = cond && (mxl[r] <= 8.f);
        }
        if (__all(cond)) {
            #pragma unroll
            for (int r = 0; r < 4; ++r)
                #pragma unroll
                for (int nt = 0; nt < 4; ++nt)
                    st[nt][r] = exp2f(st[nt][r]);
        } else {
            #pragma unroll
            for (int r = 0; r < 4; ++r) {
                float mx = mxl[r];
                mx = fmaxf(mx, __shfl_xor(mx, 1));
                mx = fmaxf(mx, __shfl_xor(mx, 2));
                mx = fmaxf(mx, __shfl_xor(mx, 4));
                mx = fmaxf(mx, __shfl_xor(mx, 8));
                float d = fmaxf(mx, 0.f);         // growth of row max (log2)
                float alpha = exp2f(-d);
                #pragma unroll
                for (int nt = 0; nt < 4; ++nt)
                    st[nt][r] = exp2f(st[nt][r] - d);
                mrow[r] += d;
                acc_l[r] *= alpha;
                #pragma unroll
                for (int dt = 0; dt < 8; ++dt) acc[dt][r] *= alpha;
            }
        }

        short* pw = Pls[w];
        #pragma unroll
        for (int nt = 0; nt < 4; ++nt)
            #pragma unroll
            for (int r = 0; r < 4; ++r) {
                int row = g * 4 + r;
                pw[row * 64 + (((nt * 2 + (li >> 3)) ^ (row & 7)) * 8) + (li & 7)]
                    = f2bf_hw(st[nt][r]);
            }
        __builtin_amdgcn_s_setprio(1);
        #pragma unroll
        for (int kk = 0; kk < 2; ++kk) {
            s16x8 af = *(const s16x8*)&pw[li * 64 + (((kk * 4 + g) ^ (li & 7)) * 8)];
            mfma_bf16(&acc_l, af, ones);          // l partial (all cols equal)
            #pragma unroll
            for (int dt = 0; dt < 8; ++dt) {
                s16x8 bfr = *(const s16x8*)&Vls[cur][(dt * 16 + li) * 64
                                                + (((kk * 4 + g) ^ (li & 7)) * 8)];
                mfma_bf16(&acc[dt], af, bfr);
            }
        }
        __builtin_amdgcn_s_setprio(0);
    }
    #undef STAGE

    // epilogue: l is lane-local in acc_l (no reduce needed)
    #pragma unroll
    for (int r = 0; r < 4; ++r) {
        float inv = 1.f / acc_l[r];
        size_t row = (size_t)bt * 2048 + q0 + w * 16 + g * 4 + r;
        #pragma unroll
        for (int dt = 0; dt < 8; ++dt)
            O[row * 1024 + hh * 128 + dt * 16 + li] = f2bf_hw(acc[dt][r] * inv);
    }
}

// ---------------- fused out-proj + residual + LN1 (one PAIR) ---------------
__global__ __launch_bounds__(256) void k_oproj(
    const short* __restrict__ O, const short* __restrict__ WoT,
    const float* __restrict__ resid, const float* __restrict__ gain,
    float* __restrict__ outp)
{
    __shared__ float red[3][16 * 128];            // 24 KB partial-acc dump
    const int w = threadIdx.x >> 6, lane = threadIdx.x & 63;
    const int g = lane >> 4, li = lane & 15;
    const int m0 = blockIdx.x * 16;               // 0..4080
    const int row = m0 + li;
    f32x4 acc[8] = {};
    #pragma unroll
    for (int kq = 0; kq < 8; ++kq) {              // ks = w*8 + kq
        int ks = w * 8 + kq;
        s16x8 a = *(const s16x8*)(O + (size_t)row * 1024 + ks * 32 + g * 8);
        #pragma unroll
        for (int nt = 0; nt < 8; ++nt) {
            s16x8 bfr = *(const s16x8*)(WoT + (size_t)(nt * 16 + li) * 1024
                                           + ks * 32 + g * 8);
            mfma_bf16(&acc[nt], a, bfr);
        }
    }
    if (w > 0) {
        #pragma unroll
        for (int nt = 0; nt < 8; ++nt)
            #pragma unroll
            for (int r = 0; r < 4; ++r)
                red[w - 1][(g * 4 + r) * 128 + nt * 16 + li] = acc[nt][r];
    }
    __syncthreads();
    if (w == 0) {
        float gv[8];
        #pragma unroll
        for (int nt = 0; nt < 8; ++nt) gv[nt] = gain[nt * 16 + li];
        #pragma unroll
        for (int r = 0; r < 4; ++r) {
            int orow = m0 + g * 4 + r;
            float s = 0.f, s2 = 0.f;
            #pragma unroll
            for (int nt = 0; nt < 8; ++nt) {
                float v = acc[nt][r]
                        + red[0][(g * 4 + r) * 128 + nt * 16 + li]
                        + red[1][(g * 4 + r) * 128 + nt * 16 + li]
                        + red[2][(g * 4 + r) * 128 + nt * 16 + li]
                        + resid[(size_t)orow * 128 + nt * 16 + li];
                acc[nt][r] = v;
                s += v; s2 += v * v;
            }
            s  += __shfl_xor(s, 1);  s  += __shfl_xor(s, 2);
            s  += __shfl_xor(s, 4);  s  += __shfl_xor(s, 8);
            s2 += __shfl_xor(s2, 1); s2 += __shfl_xor(s2, 2);
            s2 += __shfl_xor(s2, 4); s2 += __shfl_xor(s2, 8);
            float mean = s * (1.f / 128.f);
            float var  = s2 * (1.f / 128.f) - mean * mean;
            float rstd = rsqrtf(var + 1e-5f);
            #pragma unroll
            for (int nt = 0; nt < 8; ++nt)
                outp[(size_t)orow * 128 + nt * 16 + li] =
                    (acc[nt][r] - mean) * rstd * gv[nt];
        }
    }
}

// ---------------- fused FFN (r16 proven 63us version) ----------------------
__global__ __launch_bounds__(256) void k_ffn(
    const float* __restrict__ x1, const short* __restrict__ W1T,
    const short* __restrict__ W2T, const float* __restrict__ gain,
    float* __restrict__ outp)
{
    __shared__ __align__(16) short hls[4][2][16 * 64]; // [wave][mt], swizzled
    __shared__ float red[3][2][16 * 128];              // 48 KB partial-acc dump
    const int w = threadIdx.x >> 6, lane = threadIdx.x & 63;
    const int g = lane >> 4, li = lane & 15;
    const size_t m0 = (size_t)blockIdx.y * 2048 + blockIdx.x * 32;
    s16x8 xf[2][4];
    #pragma unroll
    for (int mt = 0; mt < 2; ++mt)
        #pragma unroll
        for (int ks = 0; ks < 4; ++ks) {
            const float* xr = x1 + (m0 + mt * 16 + li) * 128 + ks * 32 + g * 8;
            float4 v0 = *(const float4*)xr, v1 = *(const float4*)(xr + 4);
            xf[mt][ks] = (s16x8){ f2bf(v0.x), f2bf(v0.y), f2bf(v0.z), f2bf(v0.w),
                                  f2bf(v1.x), f2bf(v1.y), f2bf(v1.z), f2bf(v1.w) };
        }
    f32x4 acc[2][8] = {};
    #pragma unroll 2
    for (int cq = 0; cq < 8; ++cq) {              // ch = w*8 + cq
        int ch = w * 8 + cq;
        f32x4 st[2][4] = {};
        #pragma unroll
        for (int nt = 0; nt < 4; ++nt)
            #pragma unroll
            for (int ks = 0; ks < 4; ++ks) {
                s16x8 bfr = *(const s16x8*)(W1T + (size_t)(ch * 64 + nt * 16 + li) * 128
                                               + ks * 32 + g * 8);
                mfma_bf16(&st[0][nt], xf[0][ks], bfr);
                mfma_bf16(&st[1][nt], xf[1][ks], bfr);
            }
        #pragma unroll
        for (int mt = 0; mt < 2; ++mt) {
            short* hw = hls[w][mt];
            #pragma unroll
            for (int nt = 0; nt < 4; ++nt)
                #pragma unroll
                for (int r = 0; r < 4; ++r) {
                    int rw = g * 4 + r;
                    hw[rw * 64 + (((nt * 2 + (li >> 3)) ^ (rw & 7)) * 8) + (li & 7)]
                        = f2bf_hw(fmaxf(st[mt][nt][r], 0.f));
                }
        }
        #pragma unroll
        for (int kk = 0; kk < 2; ++kk) {
            s16x8 af0 = *(const s16x8*)&hls[w][0][li * 64
                                                  + (((kk * 4 + g) ^ (li & 7)) * 8)];
            s16x8 af1 = *(const s16x8*)&hls[w][1][li * 64
                                                  + (((kk * 4 + g) ^ (li & 7)) * 8)];
            #pragma unroll
            for (int nt = 0; nt < 8; ++nt) {
                s16x8 bfr = *(const s16x8*)(W2T + (size_t)(nt * 16 + li) * 2048
                                               + ch * 64 + kk * 32 + g * 8);
                mfma_bf16(&acc[0][nt], af0, bfr);
                mfma_bf16(&acc[1][nt], af1, bfr);
            }
        }
    }
    if (w > 0) {
        #pragma unroll
        for (int mt = 0; mt < 2; ++mt)
            #pragma unroll
            for (int nt = 0; nt < 8; ++nt)
                #pragma unroll
                for (int r = 0; r < 4; ++r)
                    red[w - 1][mt][(g * 4 + r) * 128 + nt * 16 + li] = acc[mt][nt][r];
    }
    __syncthreads();
    if (w == 0) {
        float gv[8];
        #pragma unroll
        for (int nt = 0; nt < 8; ++nt) gv[nt] = gain[nt * 16 + li];
        #pragma unroll
        for (int mt = 0; mt < 2; ++mt)
            #pragma unroll
            for (int r = 0; r < 4; ++r) {
                size_t orow = m0 + mt * 16 + g * 4 + r;
                float s = 0.f, s2 = 0.f;
                #pragma unroll
                for (int nt = 0; nt < 8; ++nt) {
                    float v = acc[mt][nt][r]
                            + red[0][mt][(g * 4 + r) * 128 + nt * 16 + li]
                            + red[1][mt][(g * 4 + r) * 128 + nt * 16 + li]
                            + red[2][mt][(g * 4 + r) * 128 + nt * 16 + li]
                            + x1[orow * 128 + nt * 16 + li];
                    acc[mt][nt][r] = v;
                    s += v; s2 += v * v;
                }
                s  += __shfl_xor(s, 1);  s  += __shfl_xor(s, 2);
                s  += __shfl_xor(s, 4);  s  += __shfl_xor(s, 8);
                s2 += __shfl_xor(s2, 1); s2 += __shfl_xor(s2, 2);
                s2 += __shfl_xor(s2, 4); s2 += __shfl_xor(s2, 8);
                float mean = s * (1.f / 128.f);
                float var  = s2 * (1.f / 128.f) - mean * mean;
                float rstd = rsqrtf(var + 1e-5f);
                #pragma unroll
                for (int nt = 0; nt < 8; ++nt)
                    outp[orow * 128 + nt * 16 + li] =
                        (acc[mt][nt][r] - mean) * rstd * gv[nt];
            }
    }
}

// ---------------------------------------------------------------------------
extern "C" void kernel_launch(void* const* d_in, const int* in_sizes, int n_in,
                              void* d_out, int out_size, void* d_ws, size_t ws_size,
                              hipStream_t stream)
{
    const float* x  = (const float*)d_in[0];
    const float* Wq = (const float*)d_in[1];
    const float* Wk = (const float*)d_in[2];
    const float* Wv = (const float*)d_in[3];
    const float* Wo = (const float*)d_in[4];
    const float* W1 = (const float*)d_in[5];
    const float* W2 = (const float*)d_in[6];
    const float* g1 = (const float*)d_in[7];
    const float* g2 = (const float*)d_in[8];
    float* out = (float*)d_out;
    (void)in_sizes; (void)n_in; (void)out_size; (void)ws_size;

    char* basep = (char*)d_ws;
    size_t off = 0;
    auto carve = [&](size_t bytes) {
        void* q = basep + off;
        off += (bytes + 255) & ~(size_t)255;
        return q;
    };
    // total ~34.3 MiB (proven green in r22)
    short*  WqT = (short*)carve(1024ull * 128 * 2);
    short*  WkT = (short*)carve(1024ull * 128 * 2);
    short*  WvT = (short*)carve(1024ull * 128 * 2);
    short*  WoT = (short*)carve(128ull * 1024 * 2);
    short*  W1T = (short*)carve(2048ull * 128 * 2);
    short*  W2T = (short*)carve(128ull * 2048 * 2);
    short*  Qh  = (short*)carve(16ull * 2048 * 128 * 2);   // 8 MiB (pair)
    short*  Kh  = (short*)carve(16ull * 2048 * 128 * 2);   // 8 MiB
    short*  Vt  = (short*)carve(16ull * 32 * 128 * 64 * 2);// 8 MiB
    short*  O   = (short*)carve(4096ull * 1024 * 2);       // 8 MiB (pair)

    k_transpose_all<<<4096, 256, 0, stream>>>(Wq, Wk, Wv, Wo, W1, W2,
                                              WqT, WkT, WvT, WoT, W1T, W2T);

    for (int p = 0; p < 2; ++p) {
        const float* xp = x + (size_t)p * 4096 * 128;
        float* outp = out + (size_t)p * 4096 * 128;
        k_qkv<<<dim3(32, 32, 3), 256, 0, stream>>>(xp, WqT, WkT, WvT,
                                                   Qh, Kh, Vt);
        k_attn<<<dim3(16, 8, 2), 512, 0, stream>>>(Qh, Kh, Vt, O);
        k_oproj<<<256, 256, 0, stream>>>(O, WoT, xp, g1, outp);
    }

    k_ffn<<<dim3(64, 4), 256, 0, stream>>>(out, W1T, W2T, g2, out);
}